// Round 1
// baseline (871.893 us; speedup 1.0000x reference)
//
#include <hip/hip_runtime.h>
#include <math.h>

// Problem constants
// B=64, S=512, VOCAB=32000, EMBED=512, HIDDEN=1024, ENC=1024, ATTN=256

__device__ __forceinline__ float sigmoidf_(float x) { return 1.0f / (1.0f + expf(-x)); }

// ---------------------------------------------------------------------------
// 1. Embedding gather: emb[b][e] = table[tok[b]][e]
__global__ __launch_bounds__(256) void k_embed(const int* __restrict__ tok,
                                               const float* __restrict__ table,
                                               float* __restrict__ emb) {
    int b = blockIdx.x;
    int t = tok[b];
    const float4* src = (const float4*)(table + (size_t)t * 512);
    float4* dst = (float4*)(emb + (size_t)b * 512);
    for (int i = threadIdx.x; i < 128; i += 256) dst[i] = src[i];
}

// ---------------------------------------------------------------------------
// 2. dec_proj[b][a] = sum_k h[b][k] * Wd[a][k]   (B=64 blocks, 256 threads=a)
__global__ __launch_bounds__(256) void k_dec_proj(const float* __restrict__ h,
                                                  const float* __restrict__ Wd,
                                                  float* __restrict__ dp) {
    int b = blockIdx.x;
    int a = threadIdx.x;
    __shared__ float sh[1024];
    for (int i = threadIdx.x; i < 1024; i += 256) sh[i] = h[(size_t)b * 1024 + i];
    __syncthreads();
    const float* w = Wd + (size_t)a * 1024;
    float acc = 0.f;
#pragma unroll 4
    for (int k = 0; k < 1024; k += 4) {
        float4 w4 = *(const float4*)(w + k);
        float4 h4 = *(const float4*)(sh + k);
        acc += w4.x * h4.x + w4.y * h4.y + w4.z * h4.z + w4.w * h4.w;
    }
    dp[b * 256 + a] = acc;
}

// ---------------------------------------------------------------------------
// 3. scores[b][s] = sum_a tanh(dec_proj[b][a] + sum_d enc[b][s][d]*We[a][d]) * v[a]
// Tiled GEMM: M-tile = 64 s-rows (one b), N = 256 (all a), K = 1024 step 16.
// Thread (tx,ty): rows ty*4..+3, cols {i*64 + tx*4 + 0..3 : i=0..3}
__global__ __launch_bounds__(256) void k_scores(const float* __restrict__ enc,
                                                const float* __restrict__ We,
                                                const float* __restrict__ dp,
                                                const float* __restrict__ v,
                                                float* __restrict__ scores) {
    int b  = blockIdx.x >> 3;
    int s0 = (blockIdx.x & 7) << 6;
    __shared__ float As[16][64];
    __shared__ float Bs[16][256];
    __shared__ float sdp[256];
    __shared__ float sv[256];
    __shared__ float red[64][16];
    int tid = threadIdx.x;
    int tx = tid & 15, ty = tid >> 4;
    sdp[tid] = dp[b * 256 + tid];
    sv[tid]  = v[tid];
    float acc[4][16];
#pragma unroll
    for (int i = 0; i < 4; ++i)
#pragma unroll
        for (int j = 0; j < 16; ++j) acc[i][j] = 0.f;
    const float* encB = enc + ((size_t)(b * 512 + s0)) * 1024;
    for (int k0 = 0; k0 < 1024; k0 += 16) {
        __syncthreads();
#pragma unroll
        for (int i = 0; i < 4; ++i) {
            int idx = tid + i * 256;
            int kk = idx & 15, r = idx >> 4;
            As[kk][r] = encB[(size_t)r * 1024 + k0 + kk];
        }
#pragma unroll
        for (int i = 0; i < 16; ++i) {
            int idx = tid + i * 256;
            int kk = idx & 15, a = idx >> 4;
            Bs[kk][a] = We[(size_t)a * 1024 + k0 + kk];
        }
        __syncthreads();
#pragma unroll
        for (int kk = 0; kk < 16; ++kk) {
            float4 a4 = *(const float4*)&As[kk][ty * 4];
            float av[4] = {a4.x, a4.y, a4.z, a4.w};
#pragma unroll
            for (int i = 0; i < 4; ++i) {
                float4 b4 = *(const float4*)&Bs[kk][i * 64 + tx * 4];
                float bv[4] = {b4.x, b4.y, b4.z, b4.w};
#pragma unroll
                for (int ri = 0; ri < 4; ++ri)
#pragma unroll
                    for (int cj = 0; cj < 4; ++cj) acc[ri][i * 4 + cj] += av[ri] * bv[cj];
            }
        }
    }
    // epilogue: tanh(acc + dp) * v, reduce over a
    float rsum[4] = {0.f, 0.f, 0.f, 0.f};
#pragma unroll
    for (int i = 0; i < 4; ++i) {
#pragma unroll
        for (int cj = 0; cj < 4; ++cj) {
            int c = i * 64 + tx * 4 + cj;
            float dpv = sdp[c], vv = sv[c];
#pragma unroll
            for (int ri = 0; ri < 4; ++ri)
                rsum[ri] += tanhf(acc[ri][i * 4 + cj] + dpv) * vv;
        }
    }
    __syncthreads();
#pragma unroll
    for (int ri = 0; ri < 4; ++ri) red[ty * 4 + ri][tx] = rsum[ri];
    __syncthreads();
    if (tid < 64) {
        float s = 0.f;
#pragma unroll
        for (int i = 0; i < 16; ++i) s += red[tid][i];
        scores[b * 512 + s0 + tid] = s;
    }
}

// ---------------------------------------------------------------------------
// 4. masked softmax over S=512 per batch row. Detects bool storage layout
//    (byte-packed vs int32) deterministically from the data.
__global__ __launch_bounds__(256) void k_softmax(const float* __restrict__ scores,
                                                 const unsigned* __restrict__ mask,
                                                 float* __restrict__ w) {
    int b = blockIdx.x, tid = threadIdx.x;
    __shared__ float sv[512];
    __shared__ float rbuf[256];
    __shared__ int flag;
    int bad = 0;
    for (int i = tid; i < 512; i += 256)
        if (mask[i] > 1u) bad = 1;
    if (tid == 0) flag = 0;
    __syncthreads();
    if (bad) atomicOr(&flag, 1);
    __syncthreads();
    bool u8 = (flag != 0);
    const unsigned char* m8 = (const unsigned char*)mask;
    for (int i = tid; i < 512; i += 256) {
        bool m = u8 ? (m8[(size_t)b * 512 + i] != 0) : (mask[(size_t)b * 512 + i] != 0u);
        sv[i] = m ? scores[(size_t)b * 512 + i] : -1e9f;
    }
    __syncthreads();
    float mx = fmaxf(sv[tid], sv[tid + 256]);
    rbuf[tid] = mx;
    __syncthreads();
    for (int off = 128; off > 0; off >>= 1) {
        if (tid < off) rbuf[tid] = fmaxf(rbuf[tid], rbuf[tid + off]);
        __syncthreads();
    }
    float m = rbuf[0];
    __syncthreads();
    float e0 = expf(sv[tid] - m), e1 = expf(sv[tid + 256] - m);
    rbuf[tid] = e0 + e1;
    __syncthreads();
    for (int off = 128; off > 0; off >>= 1) {
        if (tid < off) rbuf[tid] += rbuf[tid + off];
        __syncthreads();
    }
    float inv = 1.f / rbuf[0];
    w[(size_t)b * 512 + tid]       = e0 * inv;
    w[(size_t)b * 512 + tid + 256] = e1 * inv;
}

// ---------------------------------------------------------------------------
// 5. context[b][d] = sum_s w[b][s] * enc[b][s][d]. grid (4, 64), 256 thr.
__global__ __launch_bounds__(256) void k_context(const float* __restrict__ enc,
                                                 const float* __restrict__ w,
                                                 float* __restrict__ ctx) {
    int b = blockIdx.y;
    int d = blockIdx.x * 256 + threadIdx.x;
    __shared__ float sw[512];
    for (int i = threadIdx.x; i < 512; i += 256) sw[i] = w[(size_t)b * 512 + i];
    __syncthreads();
    const float* e = enc + (size_t)b * 512 * 1024 + d;
    float acc = 0.f;
#pragma unroll 8
    for (int s = 0; s < 512; ++s) acc += sw[s] * e[(size_t)s * 1024];
    ctx[b * 1024 + d] = acc;
}

// ---------------------------------------------------------------------------
// 6. gates[b][j] = sum_k X[b][k]*W[j][k], X=[emb|ctx|h] (K=2560), W=[Wih|Whh]
// N-tile 32 (grid 128), M=64 full. Thread: 4 b-rows x 2 j-cols.
__global__ __launch_bounds__(256) void k_gates(const float* __restrict__ emb,
                                               const float* __restrict__ ctx,
                                               const float* __restrict__ h,
                                               const float* __restrict__ Wih,
                                               const float* __restrict__ Whh,
                                               float* __restrict__ gates) {
    int j0 = blockIdx.x * 32;
    __shared__ float Xs[32][64];
    __shared__ float Ws[32][32];
    int tid = threadIdx.x;
    int tx = tid & 15, ty = tid >> 4;
    float acc[4][2] = {{0.f, 0.f}, {0.f, 0.f}, {0.f, 0.f}, {0.f, 0.f}};
    for (int k0 = 0; k0 < 2560; k0 += 32) {
        const float* xsrc; int xstride, xoff;
        if (k0 < 512)       { xsrc = emb; xstride = 512;  xoff = k0; }
        else if (k0 < 1536) { xsrc = ctx; xstride = 1024; xoff = k0 - 512; }
        else                { xsrc = h;   xstride = 1024; xoff = k0 - 1536; }
        const float* wsrc; int wstride, woff;
        if (k0 < 1536) { wsrc = Wih; wstride = 1536; woff = k0; }
        else           { wsrc = Whh; wstride = 1024; woff = k0 - 1536; }
        __syncthreads();
#pragma unroll
        for (int i = 0; i < 8; ++i) {
            int idx = tid + i * 256;
            int kk = idx & 31, bb = idx >> 5;
            Xs[kk][bb] = xsrc[(size_t)bb * xstride + xoff + kk];
        }
#pragma unroll
        for (int i = 0; i < 4; ++i) {
            int idx = tid + i * 256;
            int kk = idx & 31, jj = idx >> 5;
            Ws[kk][jj] = wsrc[(size_t)(j0 + jj) * wstride + woff + kk];
        }
        __syncthreads();
#pragma unroll
        for (int kk = 0; kk < 32; ++kk) {
            float4 x4 = *(const float4*)&Xs[kk][ty * 4];
            float w0 = Ws[kk][tx * 2], w1 = Ws[kk][tx * 2 + 1];
            acc[0][0] += x4.x * w0; acc[0][1] += x4.x * w1;
            acc[1][0] += x4.y * w0; acc[1][1] += x4.y * w1;
            acc[2][0] += x4.z * w0; acc[2][1] += x4.z * w1;
            acc[3][0] += x4.w * w0; acc[3][1] += x4.w * w1;
        }
    }
#pragma unroll
    for (int ri = 0; ri < 4; ++ri) {
        int bb = ty * 4 + ri;
        gates[(size_t)bb * 4096 + j0 + tx * 2]     = acc[ri][0];
        gates[(size_t)bb * 4096 + j0 + tx * 2 + 1] = acc[ri][1];
    }
}

// ---------------------------------------------------------------------------
// 7. LSTM elementwise. idx over B*H = 65536.
__global__ __launch_bounds__(256) void k_lstm(const float* __restrict__ gates,
                                              const float* __restrict__ bih,
                                              const float* __restrict__ bhh,
                                              const float* __restrict__ c0,
                                              float* __restrict__ out_h,
                                              float* __restrict__ out_c) {
    int idx = blockIdx.x * 256 + threadIdx.x;
    int b = idx >> 10, hh = idx & 1023;
    const float* g = gates + (size_t)b * 4096;
    float ig = g[hh]        + bih[hh]        + bhh[hh];
    float fg = g[1024 + hh] + bih[1024 + hh] + bhh[1024 + hh];
    float gg = g[2048 + hh] + bih[2048 + hh] + bhh[2048 + hh];
    float og = g[3072 + hh] + bih[3072 + hh] + bhh[3072 + hh];
    float c_old = c0[idx];
    float nc = sigmoidf_(fg) * c_old + sigmoidf_(ig) * tanhf(gg);
    float nh = sigmoidf_(og) * tanhf(nc);
    out_h[idx] = nh;
    out_c[idx] = nc;
}

// ---------------------------------------------------------------------------
// 8. readout: T[b][j] = tanh(sum_k Y[b][k]*Wo[j][k] + bo[j]), Y=[nh|ctx|emb]
// N=512, N-tile 32 (grid 16)
__global__ __launch_bounds__(256) void k_readout(const float* __restrict__ nh,
                                                 const float* __restrict__ ctx,
                                                 const float* __restrict__ emb,
                                                 const float* __restrict__ Wo,
                                                 const float* __restrict__ bo,
                                                 float* __restrict__ T) {
    int j0 = blockIdx.x * 32;
    __shared__ float Xs[32][64];
    __shared__ float Ws[32][32];
    int tid = threadIdx.x;
    int tx = tid & 15, ty = tid >> 4;
    float acc[4][2] = {{0.f, 0.f}, {0.f, 0.f}, {0.f, 0.f}, {0.f, 0.f}};
    for (int k0 = 0; k0 < 2560; k0 += 32) {
        const float* xsrc; int xstride, xoff;
        if (k0 < 1024)      { xsrc = nh;  xstride = 1024; xoff = k0; }
        else if (k0 < 2048) { xsrc = ctx; xstride = 1024; xoff = k0 - 1024; }
        else                { xsrc = emb; xstride = 512;  xoff = k0 - 2048; }
        __syncthreads();
#pragma unroll
        for (int i = 0; i < 8; ++i) {
            int idx = tid + i * 256;
            int kk = idx & 31, bb = idx >> 5;
            Xs[kk][bb] = xsrc[(size_t)bb * xstride + xoff + kk];
        }
#pragma unroll
        for (int i = 0; i < 4; ++i) {
            int idx = tid + i * 256;
            int kk = idx & 31, jj = idx >> 5;
            Ws[kk][jj] = Wo[(size_t)(j0 + jj) * 2560 + k0 + kk];
        }
        __syncthreads();
#pragma unroll
        for (int kk = 0; kk < 32; ++kk) {
            float4 x4 = *(const float4*)&Xs[kk][ty * 4];
            float w0 = Ws[kk][tx * 2], w1 = Ws[kk][tx * 2 + 1];
            acc[0][0] += x4.x * w0; acc[0][1] += x4.x * w1;
            acc[1][0] += x4.y * w0; acc[1][1] += x4.y * w1;
            acc[2][0] += x4.z * w0; acc[2][1] += x4.z * w1;
            acc[3][0] += x4.w * w0; acc[3][1] += x4.w * w1;
        }
    }
#pragma unroll
    for (int ri = 0; ri < 4; ++ri) {
        int bb = ty * 4 + ri;
        int j = j0 + tx * 2;
        T[(size_t)bb * 512 + j]     = tanhf(acc[ri][0] + bo[j]);
        T[(size_t)bb * 512 + j + 1] = tanhf(acc[ri][1] + bo[j + 1]);
    }
}

// ---------------------------------------------------------------------------
// 9. logits[b][v] = sum_j T[b][j] * table[v][j]. N=32000, N-tile 128 (grid 250)
// Thread: 4 b-rows x 8 cols {i*64 + tx*4 + 0..3 : i=0..1}
__global__ __launch_bounds__(256) void k_logits(const float* __restrict__ T,
                                                const float* __restrict__ table,
                                                float* __restrict__ out) {
    int j0 = blockIdx.x * 128;
    __shared__ float Ts[32][64];
    __shared__ float Es[32][128];
    int tid = threadIdx.x;
    int tx = tid & 15, ty = tid >> 4;
    float acc[4][8];
#pragma unroll
    for (int i = 0; i < 4; ++i)
#pragma unroll
        for (int j = 0; j < 8; ++j) acc[i][j] = 0.f;
    for (int k0 = 0; k0 < 512; k0 += 32) {
        __syncthreads();
#pragma unroll
        for (int i = 0; i < 8; ++i) {
            int idx = tid + i * 256;
            int kk = idx & 31, bb = idx >> 5;
            Ts[kk][bb] = T[(size_t)bb * 512 + k0 + kk];
        }
#pragma unroll
        for (int i = 0; i < 16; ++i) {
            int idx = tid + i * 256;
            int kk = idx & 31, jj = idx >> 5;
            Es[kk][jj] = table[(size_t)(j0 + jj) * 512 + k0 + kk];
        }
        __syncthreads();
#pragma unroll
        for (int kk = 0; kk < 32; ++kk) {
            float4 x4 = *(const float4*)&Ts[kk][ty * 4];
            float xv[4] = {x4.x, x4.y, x4.z, x4.w};
#pragma unroll
            for (int i = 0; i < 2; ++i) {
                float4 e4 = *(const float4*)&Es[kk][i * 64 + tx * 4];
                float ev[4] = {e4.x, e4.y, e4.z, e4.w};
#pragma unroll
                for (int ri = 0; ri < 4; ++ri)
#pragma unroll
                    for (int cj = 0; cj < 4; ++cj) acc[ri][i * 4 + cj] += xv[ri] * ev[cj];
            }
        }
    }
#pragma unroll
    for (int ri = 0; ri < 4; ++ri) {
        int bb = ty * 4 + ri;
#pragma unroll
        for (int i = 0; i < 2; ++i)
#pragma unroll
            for (int cj = 0; cj < 4; ++cj)
                out[(size_t)bb * 32000 + j0 + i * 64 + tx * 4 + cj] = acc[ri][i * 4 + cj];
    }
}

// ---------------------------------------------------------------------------
extern "C" void kernel_launch(void* const* d_in, const int* in_sizes, int n_in,
                              void* d_out, int out_size, void* d_ws, size_t ws_size,
                              hipStream_t stream) {
    const int*      tok   = (const int*)d_in[0];
    const float*    h0    = (const float*)d_in[1];
    const float*    c0    = (const float*)d_in[2];
    const float*    enc   = (const float*)d_in[3];
    const unsigned* mask  = (const unsigned*)d_in[4];
    const float*    table = (const float*)d_in[5];
    const float*    We    = (const float*)d_in[6];
    const float*    Wd    = (const float*)d_in[7];
    const float*    va    = (const float*)d_in[8];
    const float*    Wih   = (const float*)d_in[9];
    const float*    Whh   = (const float*)d_in[10];
    const float*    bih   = (const float*)d_in[11];
    const float*    bhh   = (const float*)d_in[12];
    const float*    Wo    = (const float*)d_in[13];
    const float*    bo    = (const float*)d_in[14];

    float* out    = (float*)d_out;
    float* logits = out;                      // 64*32000
    float* out_h  = out + 2048000;            // 65536
    float* out_c  = out + 2048000 + 65536;    // 65536
    float* out_w  = out + 2048000 + 131072;   // 32768

    float* ws     = (float*)d_ws;
    float* emb    = ws;             // 32768
    float* dp     = ws + 32768;     // 16384
    float* scores = ws + 49152;     // 32768
    float* ctx    = ws + 81920;     // 65536
    float* gates  = ws + 147456;    // 262144
    float* T      = ws + 409600;    // 32768

    k_embed   <<<64, 256, 0, stream>>>(tok, table, emb);
    k_dec_proj<<<64, 256, 0, stream>>>(h0, Wd, dp);
    k_scores  <<<512, 256, 0, stream>>>(enc, We, dp, va, scores);
    k_softmax <<<64, 256, 0, stream>>>(scores, mask, out_w);
    k_context <<<dim3(4, 64), 256, 0, stream>>>(enc, out_w, ctx);
    k_gates   <<<128, 256, 0, stream>>>(emb, ctx, h0, Wih, Whh, gates);
    k_lstm    <<<256, 256, 0, stream>>>(gates, bih, bhh, c0, out_h, out_c);
    k_readout <<<16, 256, 0, stream>>>(out_h, ctx, emb, Wo, bo, T);
    k_logits  <<<250, 256, 0, stream>>>(T, table, logits);
}

// Round 2
// 504.096 us; speedup vs baseline: 1.7296x; 1.7296x over previous
//
#include <hip/hip_runtime.h>
#include <hip/hip_bf16.h>
#include <math.h>

// B=64, S=512, VOCAB=32000, EMBED=512, HIDDEN=1024, ENC=1024, ATTN=256

typedef float f32x4 __attribute__((ext_vector_type(4)));
typedef short s16x8 __attribute__((ext_vector_type(8)));

__device__ __forceinline__ float sigmoidf_(float x) { return 1.0f / (1.0f + expf(-x)); }

__device__ __forceinline__ ushort f2bf(float f) {
    __hip_bfloat16 h = __float2bfloat16(f);
    return *reinterpret_cast<ushort*>(&h);
}

// ---------------------------------------------------------------------------
// 1. Embedding gather
__global__ __launch_bounds__(256) void k_embed(const int* __restrict__ tok,
                                               const float* __restrict__ table,
                                               float* __restrict__ emb) {
    int b = blockIdx.x;
    int t = tok[b];
    const float4* src = (const float4*)(table + (size_t)t * 512);
    float4* dst = (float4*)(emb + (size_t)b * 512);
    for (int i = threadIdx.x; i < 128; i += 256) dst[i] = src[i];
}

// ---------------------------------------------------------------------------
// 2. dec_proj[b][a] = sum_k h[b][k] * Wd[a][k]
__global__ __launch_bounds__(256) void k_dec_proj(const float* __restrict__ h,
                                                  const float* __restrict__ Wd,
                                                  float* __restrict__ dp) {
    int b = blockIdx.x;
    int a = threadIdx.x;
    __shared__ float sh[1024];
    for (int i = threadIdx.x; i < 1024; i += 256) sh[i] = h[(size_t)b * 1024 + i];
    __syncthreads();
    const float* w = Wd + (size_t)a * 1024;
    float acc = 0.f;
#pragma unroll 4
    for (int k = 0; k < 1024; k += 4) {
        float4 w4 = *(const float4*)(w + k);
        float4 h4 = *(const float4*)(sh + k);
        acc += w4.x * h4.x + w4.y * h4.y + w4.z * h4.z + w4.w * h4.w;
    }
    dp[b * 256 + a] = acc;
}

// ---------------------------------------------------------------------------
// 2b. Convert We [256][1024] f32 -> bf16 (row-major, K-contiguous = B^T layout)
__global__ __launch_bounds__(256) void k_convW(const float* __restrict__ W,
                                               ushort* __restrict__ Wb) {
    int i = blockIdx.x * 256 + threadIdx.x;   // group of 4 elements
    float4 f = ((const float4*)W)[i];
    ushort4 o;
    o.x = f2bf(f.x); o.y = f2bf(f.y); o.z = f2bf(f.z); o.w = f2bf(f.w);
    ((ushort4*)Wb)[i] = o;
}

// ---------------------------------------------------------------------------
// 3. scores via MFMA: per block (b, 64-row s-tile), 4 waves x 16 rows x 256 cols.
//    A = enc rows (f32 -> bf16 in-reg), B = Wbf (bf16, K-contiguous), no GEMM LDS.
//    Epilogue fuses +dp, tanh, *v, col-reduce.
__global__ __launch_bounds__(256) void k_scores_mfma(const float* __restrict__ enc,
                                                     const ushort* __restrict__ Wbf,
                                                     const float* __restrict__ dp,
                                                     const float* __restrict__ v,
                                                     float* __restrict__ scores) {
    int b  = blockIdx.x >> 3;
    int s0 = (blockIdx.x & 7) << 6;
    int tid = threadIdx.x;
    int wave = tid >> 6, lane = tid & 63;
    int lan = lane & 15, lk = lane >> 4;      // lan: row/col within frag, lk: k-subchunk

    __shared__ float sdp[256], sv[256];
    sdp[tid] = dp[b * 256 + tid];
    sv[tid]  = v[tid];
    __syncthreads();

    int row = s0 + wave * 16 + lan;
    const float*  encRow = enc + ((size_t)(b * 512 + row)) * 1024 + lk * 8;
    const ushort* pbBase = Wbf + (size_t)lan * 1024 + lk * 8;

    f32x4 acc[16];
#pragma unroll
    for (int ni = 0; ni < 16; ++ni) acc[ni] = (f32x4){0.f, 0.f, 0.f, 0.f};

    for (int k0 = 0; k0 < 1024; k0 += 32) {
        float4 f0 = *(const float4*)(encRow + k0);
        float4 f1 = *(const float4*)(encRow + k0 + 4);
        s16x8 af;
        af[0] = (short)f2bf(f0.x); af[1] = (short)f2bf(f0.y);
        af[2] = (short)f2bf(f0.z); af[3] = (short)f2bf(f0.w);
        af[4] = (short)f2bf(f1.x); af[5] = (short)f2bf(f1.y);
        af[6] = (short)f2bf(f1.z); af[7] = (short)f2bf(f1.w);
        const ushort* pb = pbBase + k0;
#pragma unroll
        for (int ni = 0; ni < 16; ++ni) {
            s16x8 bf = *(const s16x8*)(pb + ni * 16384);   // 16 cols * 1024 stride
            acc[ni] = __builtin_amdgcn_mfma_f32_16x16x32_bf16(af, bf, acc[ni], 0, 0, 0);
        }
    }

    // epilogue: sum_a tanh(acc + dp[a]) * v[a]; D layout: col=lane&15, row=lk*4+reg
    float rsum[4] = {0.f, 0.f, 0.f, 0.f};
#pragma unroll
    for (int ni = 0; ni < 16; ++ni) {
        int a = ni * 16 + lan;
        float dpv = sdp[a], vv = sv[a];
#pragma unroll
        for (int r = 0; r < 4; ++r) {
            float x = acc[ni][r] + dpv;
            float t = 1.f - 2.f / (1.f + __expf(2.f * x));   // tanh
            rsum[r] += t * vv;
        }
    }
#pragma unroll
    for (int off = 1; off < 16; off <<= 1) {
#pragma unroll
        for (int r = 0; r < 4; ++r) rsum[r] += __shfl_xor(rsum[r], off);
    }
    if (lan == 0) {
#pragma unroll
        for (int r = 0; r < 4; ++r)
            scores[b * 512 + s0 + wave * 16 + lk * 4 + r] = rsum[r];
    }
}

// ---------------------------------------------------------------------------
// 4. masked softmax (detects bool storage layout)
__global__ __launch_bounds__(256) void k_softmax(const float* __restrict__ scores,
                                                 const unsigned* __restrict__ mask,
                                                 float* __restrict__ w) {
    int b = blockIdx.x, tid = threadIdx.x;
    __shared__ float sv[512];
    __shared__ float rbuf[256];
    __shared__ int flag;
    int bad = 0;
    for (int i = tid; i < 512; i += 256)
        if (mask[i] > 1u) bad = 1;
    if (tid == 0) flag = 0;
    __syncthreads();
    if (bad) atomicOr(&flag, 1);
    __syncthreads();
    bool u8 = (flag != 0);
    const unsigned char* m8 = (const unsigned char*)mask;
    for (int i = tid; i < 512; i += 256) {
        bool m = u8 ? (m8[(size_t)b * 512 + i] != 0) : (mask[(size_t)b * 512 + i] != 0u);
        sv[i] = m ? scores[(size_t)b * 512 + i] : -1e9f;
    }
    __syncthreads();
    float mx = fmaxf(sv[tid], sv[tid + 256]);
    rbuf[tid] = mx;
    __syncthreads();
    for (int off = 128; off > 0; off >>= 1) {
        if (tid < off) rbuf[tid] = fmaxf(rbuf[tid], rbuf[tid + off]);
        __syncthreads();
    }
    float m = rbuf[0];
    __syncthreads();
    float e0 = expf(sv[tid] - m), e1 = expf(sv[tid + 256] - m);
    rbuf[tid] = e0 + e1;
    __syncthreads();
    for (int off = 128; off > 0; off >>= 1) {
        if (tid < off) rbuf[tid] += rbuf[tid + off];
        __syncthreads();
    }
    float inv = 1.f / rbuf[0];
    w[(size_t)b * 512 + tid]       = e0 * inv;
    w[(size_t)b * 512 + tid + 256] = e1 * inv;
}

// ---------------------------------------------------------------------------
// 5a. context partials over s-chunks of 128. grid (4, 64, 4)
__global__ __launch_bounds__(256) void k_context_part(const float* __restrict__ enc,
                                                      const float* __restrict__ w,
                                                      float* __restrict__ part) {
    int b = blockIdx.y;
    int d = blockIdx.x * 256 + threadIdx.x;
    int sc = blockIdx.z;
    __shared__ float sw[128];
    if (threadIdx.x < 128) sw[threadIdx.x] = w[(size_t)b * 512 + sc * 128 + threadIdx.x];
    __syncthreads();
    const float* e = enc + ((size_t)b * 512 + sc * 128) * 1024 + d;
    float acc = 0.f;
#pragma unroll 8
    for (int s = 0; s < 128; ++s) acc += sw[s] * e[(size_t)s * 1024];
    part[(size_t)sc * 65536 + b * 1024 + d] = acc;
}

// 5b. reduce 4 partials
__global__ __launch_bounds__(256) void k_ctx_reduce(const float* __restrict__ part,
                                                    float* __restrict__ ctx) {
    int i = blockIdx.x * 256 + threadIdx.x;
    ctx[i] = part[i] + part[65536 + i] + part[131072 + i] + part[196608 + i];
}

// ---------------------------------------------------------------------------
// 6. gates GEMM (padded LDS: 4-way max on staging writes)
__global__ __launch_bounds__(256) void k_gates(const float* __restrict__ emb,
                                               const float* __restrict__ ctx,
                                               const float* __restrict__ h,
                                               const float* __restrict__ Wih,
                                               const float* __restrict__ Whh,
                                               float* __restrict__ gates) {
    int j0 = blockIdx.x * 32;
    __shared__ float Xs[32][68];
    __shared__ float Ws[32][36];
    int tid = threadIdx.x;
    int tx = tid & 15, ty = tid >> 4;
    float acc[4][2] = {{0.f, 0.f}, {0.f, 0.f}, {0.f, 0.f}, {0.f, 0.f}};
    for (int k0 = 0; k0 < 2560; k0 += 32) {
        const float* xsrc; int xstride, xoff;
        if (k0 < 512)       { xsrc = emb; xstride = 512;  xoff = k0; }
        else if (k0 < 1536) { xsrc = ctx; xstride = 1024; xoff = k0 - 512; }
        else                { xsrc = h;   xstride = 1024; xoff = k0 - 1536; }
        const float* wsrc; int wstride, woff;
        if (k0 < 1536) { wsrc = Wih; wstride = 1536; woff = k0; }
        else           { wsrc = Whh; wstride = 1024; woff = k0 - 1536; }
        __syncthreads();
#pragma unroll
        for (int i = 0; i < 8; ++i) {
            int idx = tid + i * 256;
            int kk = idx & 31, bb = idx >> 5;
            Xs[kk][bb] = xsrc[(size_t)bb * xstride + xoff + kk];
        }
#pragma unroll
        for (int i = 0; i < 4; ++i) {
            int idx = tid + i * 256;
            int kk = idx & 31, jj = idx >> 5;
            Ws[kk][jj] = wsrc[(size_t)(j0 + jj) * wstride + woff + kk];
        }
        __syncthreads();
#pragma unroll
        for (int kk = 0; kk < 32; ++kk) {
            float4 x4 = *(const float4*)&Xs[kk][ty * 4];
            float w0 = Ws[kk][tx * 2], w1 = Ws[kk][tx * 2 + 1];
            acc[0][0] += x4.x * w0; acc[0][1] += x4.x * w1;
            acc[1][0] += x4.y * w0; acc[1][1] += x4.y * w1;
            acc[2][0] += x4.z * w0; acc[2][1] += x4.z * w1;
            acc[3][0] += x4.w * w0; acc[3][1] += x4.w * w1;
        }
    }
#pragma unroll
    for (int ri = 0; ri < 4; ++ri) {
        int bb = ty * 4 + ri;
        gates[(size_t)bb * 4096 + j0 + tx * 2]     = acc[ri][0];
        gates[(size_t)bb * 4096 + j0 + tx * 2 + 1] = acc[ri][1];
    }
}

// ---------------------------------------------------------------------------
// 7. LSTM elementwise
__global__ __launch_bounds__(256) void k_lstm(const float* __restrict__ gates,
                                              const float* __restrict__ bih,
                                              const float* __restrict__ bhh,
                                              const float* __restrict__ c0,
                                              float* __restrict__ out_h,
                                              float* __restrict__ out_c) {
    int idx = blockIdx.x * 256 + threadIdx.x;
    int b = idx >> 10, hh = idx & 1023;
    const float* g = gates + (size_t)b * 4096;
    float ig = g[hh]        + bih[hh]        + bhh[hh];
    float fg = g[1024 + hh] + bih[1024 + hh] + bhh[1024 + hh];
    float gg = g[2048 + hh] + bih[2048 + hh] + bhh[2048 + hh];
    float og = g[3072 + hh] + bih[3072 + hh] + bhh[3072 + hh];
    float c_old = c0[idx];
    float nc = sigmoidf_(fg) * c_old + sigmoidf_(ig) * tanhf(gg);
    float nh = sigmoidf_(og) * tanhf(nc);
    out_h[idx] = nh;
    out_c[idx] = nc;
}

// ---------------------------------------------------------------------------
// 8. readout (padded LDS)
__global__ __launch_bounds__(256) void k_readout(const float* __restrict__ nh,
                                                 const float* __restrict__ ctx,
                                                 const float* __restrict__ emb,
                                                 const float* __restrict__ Wo,
                                                 const float* __restrict__ bo,
                                                 float* __restrict__ T) {
    int j0 = blockIdx.x * 32;
    __shared__ float Xs[32][68];
    __shared__ float Ws[32][36];
    int tid = threadIdx.x;
    int tx = tid & 15, ty = tid >> 4;
    float acc[4][2] = {{0.f, 0.f}, {0.f, 0.f}, {0.f, 0.f}, {0.f, 0.f}};
    for (int k0 = 0; k0 < 2560; k0 += 32) {
        const float* xsrc; int xstride, xoff;
        if (k0 < 1024)      { xsrc = nh;  xstride = 1024; xoff = k0; }
        else if (k0 < 2048) { xsrc = ctx; xstride = 1024; xoff = k0 - 1024; }
        else                { xsrc = emb; xstride = 512;  xoff = k0 - 2048; }
        __syncthreads();
#pragma unroll
        for (int i = 0; i < 8; ++i) {
            int idx = tid + i * 256;
            int kk = idx & 31, bb = idx >> 5;
            Xs[kk][bb] = xsrc[(size_t)bb * xstride + xoff + kk];
        }
#pragma unroll
        for (int i = 0; i < 4; ++i) {
            int idx = tid + i * 256;
            int kk = idx & 31, jj = idx >> 5;
            Ws[kk][jj] = Wo[(size_t)(j0 + jj) * 2560 + k0 + kk];
        }
        __syncthreads();
#pragma unroll
        for (int kk = 0; kk < 32; ++kk) {
            float4 x4 = *(const float4*)&Xs[kk][ty * 4];
            float w0 = Ws[kk][tx * 2], w1 = Ws[kk][tx * 2 + 1];
            acc[0][0] += x4.x * w0; acc[0][1] += x4.x * w1;
            acc[1][0] += x4.y * w0; acc[1][1] += x4.y * w1;
            acc[2][0] += x4.z * w0; acc[2][1] += x4.z * w1;
            acc[3][0] += x4.w * w0; acc[3][1] += x4.w * w1;
        }
    }
#pragma unroll
    for (int ri = 0; ri < 4; ++ri) {
        int bb = ty * 4 + ri;
        int j = j0 + tx * 2;
        T[(size_t)bb * 512 + j]     = tanhf(acc[ri][0] + bo[j]);
        T[(size_t)bb * 512 + j + 1] = tanhf(acc[ri][1] + bo[j + 1]);
    }
}

// ---------------------------------------------------------------------------
// 9. logits (padded LDS)
__global__ __launch_bounds__(256) void k_logits(const float* __restrict__ T,
                                                const float* __restrict__ table,
                                                float* __restrict__ out) {
    int j0 = blockIdx.x * 128;
    __shared__ float Ts[32][68];
    __shared__ float Es[32][132];
    int tid = threadIdx.x;
    int tx = tid & 15, ty = tid >> 4;
    float acc[4][8];
#pragma unroll
    for (int i = 0; i < 4; ++i)
#pragma unroll
        for (int j = 0; j < 8; ++j) acc[i][j] = 0.f;
    for (int k0 = 0; k0 < 512; k0 += 32) {
        __syncthreads();
#pragma unroll
        for (int i = 0; i < 8; ++i) {
            int idx = tid + i * 256;
            int kk = idx & 31, bb = idx >> 5;
            Ts[kk][bb] = T[(size_t)bb * 512 + k0 + kk];
        }
#pragma unroll
        for (int i = 0; i < 16; ++i) {
            int idx = tid + i * 256;
            int kk = idx & 31, jj = idx >> 5;
            Es[kk][jj] = table[(size_t)(j0 + jj) * 512 + k0 + kk];
        }
        __syncthreads();
#pragma unroll
        for (int kk = 0; kk < 32; ++kk) {
            float4 x4 = *(const float4*)&Ts[kk][ty * 4];
            float xv[4] = {x4.x, x4.y, x4.z, x4.w};
#pragma unroll
            for (int i = 0; i < 2; ++i) {
                float4 e4 = *(const float4*)&Es[kk][i * 64 + tx * 4];
                float ev[4] = {e4.x, e4.y, e4.z, e4.w};
#pragma unroll
                for (int ri = 0; ri < 4; ++ri)
#pragma unroll
                    for (int cj = 0; cj < 4; ++cj) acc[ri][i * 4 + cj] += xv[ri] * ev[cj];
            }
        }
    }
#pragma unroll
    for (int ri = 0; ri < 4; ++ri) {
        int bb = ty * 4 + ri;
#pragma unroll
        for (int i = 0; i < 2; ++i)
#pragma unroll
            for (int cj = 0; cj < 4; ++cj)
                out[(size_t)bb * 32000 + j0 + i * 64 + tx * 4 + cj] = acc[ri][i * 4 + cj];
    }
}

// ---------------------------------------------------------------------------
extern "C" void kernel_launch(void* const* d_in, const int* in_sizes, int n_in,
                              void* d_out, int out_size, void* d_ws, size_t ws_size,
                              hipStream_t stream) {
    const int*      tok   = (const int*)d_in[0];
    const float*    h0    = (const float*)d_in[1];
    const float*    c0    = (const float*)d_in[2];
    const float*    enc   = (const float*)d_in[3];
    const unsigned* mask  = (const unsigned*)d_in[4];
    const float*    table = (const float*)d_in[5];
    const float*    We    = (const float*)d_in[6];
    const float*    Wd    = (const float*)d_in[7];
    const float*    va    = (const float*)d_in[8];
    const float*    Wih   = (const float*)d_in[9];
    const float*    Whh   = (const float*)d_in[10];
    const float*    bih   = (const float*)d_in[11];
    const float*    bhh   = (const float*)d_in[12];
    const float*    Wo    = (const float*)d_in[13];
    const float*    bo    = (const float*)d_in[14];

    float* out    = (float*)d_out;
    float* logits = out;                      // 64*32000
    float* out_h  = out + 2048000;            // 65536
    float* out_c  = out + 2048000 + 65536;    // 65536
    float* out_w  = out + 2048000 + 131072;   // 32768

    float* ws     = (float*)d_ws;
    float* emb    = ws;             // 32768
    float* dp     = ws + 32768;     // 16384
    float* scores = ws + 49152;     // 32768
    float* ctx    = ws + 81920;     // 65536
    float* gates  = ws + 147456;    // 262144 (also aliased as ctx partials)
    float* T      = ws + 409600;    // 32768
    ushort* Wbf   = (ushort*)(ws + 442368);   // 262144 bf16

    k_embed       <<<64, 256, 0, stream>>>(tok, table, emb);
    k_convW       <<<256, 256, 0, stream>>>(We, Wbf);
    k_dec_proj    <<<64, 256, 0, stream>>>(h0, Wd, dp);
    k_scores_mfma <<<512, 256, 0, stream>>>(enc, Wbf, dp, va, scores);
    k_softmax     <<<64, 256, 0, stream>>>(scores, mask, out_w);
    k_context_part<<<dim3(4, 64, 4), 256, 0, stream>>>(enc, out_w, gates);
    k_ctx_reduce  <<<256, 256, 0, stream>>>(gates, ctx);
    k_gates       <<<128, 256, 0, stream>>>(emb, ctx, h0, Wih, Whh, gates);
    k_lstm        <<<256, 256, 0, stream>>>(gates, bih, bhh, c0, out_h, out_c);
    k_readout     <<<16, 256, 0, stream>>>(out_h, ctx, emb, Wo, bo, T);
    k_logits      <<<250, 256, 0, stream>>>(T, table, logits);
}

// Round 3
// 268.731 us; speedup vs baseline: 3.2445x; 1.8758x over previous
//
#include <hip/hip_runtime.h>
#include <hip/hip_bf16.h>
#include <math.h>

// B=64, S=512, VOCAB=32000, EMBED=512, HIDDEN=1024, ENC=1024, ATTN=256

typedef float f32x4 __attribute__((ext_vector_type(4)));
typedef short s16x8 __attribute__((ext_vector_type(8)));

__device__ __forceinline__ float sigmoidf_(float x) { return 1.0f / (1.0f + expf(-x)); }

__device__ __forceinline__ ushort f2bf(float f) {
    __hip_bfloat16 h = __float2bfloat16(f);
    return *reinterpret_cast<ushort*>(&h);
}

// ---------------------------------------------------------------------------
// 1. Embedding gather
__global__ __launch_bounds__(256) void k_embed(const int* __restrict__ tok,
                                               const float* __restrict__ table,
                                               float* __restrict__ emb) {
    int b = blockIdx.x;
    int t = tok[b];
    const float4* src = (const float4*)(table + (size_t)t * 512);
    float4* dst = (float4*)(emb + (size_t)b * 512);
    for (int i = threadIdx.x; i < 128; i += 256) dst[i] = src[i];
}

// ---------------------------------------------------------------------------
// 2. dec_proj[b][a] = sum_k h[b][k] * Wd[a][k]
__global__ __launch_bounds__(256) void k_dec_proj(const float* __restrict__ h,
                                                  const float* __restrict__ Wd,
                                                  float* __restrict__ dp) {
    int b = blockIdx.x;
    int a = threadIdx.x;
    __shared__ float sh[1024];
    for (int i = threadIdx.x; i < 1024; i += 256) sh[i] = h[(size_t)b * 1024 + i];
    __syncthreads();
    const float* w = Wd + (size_t)a * 1024;
    float acc = 0.f;
#pragma unroll 4
    for (int k = 0; k < 1024; k += 4) {
        float4 w4 = *(const float4*)(w + k);
        float4 h4 = *(const float4*)(sh + k);
        acc += w4.x * h4.x + w4.y * h4.y + w4.z * h4.z + w4.w * h4.w;
    }
    dp[b * 256 + a] = acc;
}

// ---------------------------------------------------------------------------
// 2b. Convert We [256][1024] f32 -> bf16
__global__ __launch_bounds__(256) void k_convW(const float* __restrict__ W,
                                               ushort* __restrict__ Wb) {
    int i = blockIdx.x * 256 + threadIdx.x;
    float4 f = ((const float4*)W)[i];
    ushort4 o;
    o.x = f2bf(f.x); o.y = f2bf(f.y); o.z = f2bf(f.z); o.w = f2bf(f.w);
    ((ushort4*)Wb)[i] = o;
}

// ---------------------------------------------------------------------------
// 3. scores via MFMA, LDS-staged. Block = (b, 64 s-rows); 4 waves x 16 rows x 256 cols.
//    K-chunk 64. LDS slots (16B = 8 bf16): slot = row*8 + (koct ^ (row&7)) -- XOR
//    swizzle keeps both staging writes and fragment reads bank-uniform.
__global__ __launch_bounds__(256, 3) void k_scores_mfma(const float* __restrict__ enc,
                                                        const ushort* __restrict__ Wbf,
                                                        const float* __restrict__ dp,
                                                        const float* __restrict__ v,
                                                        float* __restrict__ scores) {
    int b  = blockIdx.x >> 3;
    int s0 = (blockIdx.x & 7) << 6;
    int tid = threadIdx.x;
    int wave = tid >> 6, lane = tid & 63;
    int lan = lane & 15, lk = lane >> 4;

    __shared__ s16x8 Al[512];    // 8 KB : 64 rows x 8 koct
    __shared__ s16x8 Bl[2048];   // 32 KB: 256 a  x 8 koct
    __shared__ float sdp[256], sv[256];

    sdp[tid] = dp[b * 256 + tid];
    sv[tid]  = v[tid];

    const float* encB = enc + ((size_t)(b * 512 + s0)) * 1024;

    f32x4 acc[16];
#pragma unroll
    for (int ni = 0; ni < 16; ++ni) acc[ni] = (f32x4){0.f, 0.f, 0.f, 0.f};

    for (int k0 = 0; k0 < 1024; k0 += 64) {
        __syncthreads();
        // stage A: 64 rows x 64 k (f32 -> bf16), 512 slots, coalesced reads
#pragma unroll
        for (int it = 0; it < 2; ++it) {
            int idx = tid + it * 256;
            int row = idx >> 3, koct = idx & 7;
            const float* src = encB + (size_t)row * 1024 + k0 + koct * 8;
            float4 f0 = *(const float4*)src;
            float4 f1 = *(const float4*)(src + 4);
            s16x8 pk;
            pk[0] = (short)f2bf(f0.x); pk[1] = (short)f2bf(f0.y);
            pk[2] = (short)f2bf(f0.z); pk[3] = (short)f2bf(f0.w);
            pk[4] = (short)f2bf(f1.x); pk[5] = (short)f2bf(f1.y);
            pk[6] = (short)f2bf(f1.z); pk[7] = (short)f2bf(f1.w);
            Al[row * 8 + (koct ^ (row & 7))] = pk;
        }
        // stage B: 256 a x 64 k bf16, 2048 slots, coalesced reads
#pragma unroll
        for (int it = 0; it < 8; ++it) {
            int idx = tid + it * 256;
            int a = idx >> 3, koct = idx & 7;
            s16x8 wv = *(const s16x8*)(Wbf + (size_t)a * 1024 + k0 + koct * 8);
            Bl[a * 8 + (koct ^ (a & 7))] = wv;
        }
        __syncthreads();
#pragma unroll
        for (int ks = 0; ks < 2; ++ks) {
            int arow = wave * 16 + lan;
            int akoct = ks * 4 + lk;
            s16x8 af = Al[arow * 8 + (akoct ^ (arow & 7))];
#pragma unroll
            for (int ni = 0; ni < 16; ++ni) {
                int a = ni * 16 + lan;
                s16x8 bf = Bl[a * 8 + (akoct ^ (a & 7))];
                acc[ni] = __builtin_amdgcn_mfma_f32_16x16x32_bf16(af, bf, acc[ni], 0, 0, 0);
            }
        }
    }

    // epilogue: sum_a tanh(acc + dp[a]) * v[a]; D layout: col=lane&15, row=lk*4+reg
    float rsum[4] = {0.f, 0.f, 0.f, 0.f};
#pragma unroll
    for (int ni = 0; ni < 16; ++ni) {
        int a = ni * 16 + lan;
        float dpv = sdp[a], vv = sv[a];
#pragma unroll
        for (int r = 0; r < 4; ++r) {
            float x = acc[ni][r] + dpv;
            float t = 1.f - 2.f / (1.f + __expf(2.f * x));   // tanh
            rsum[r] += t * vv;
        }
    }
#pragma unroll
    for (int off = 1; off < 16; off <<= 1) {
#pragma unroll
        for (int r = 0; r < 4; ++r) rsum[r] += __shfl_xor(rsum[r], off);
    }
    if (lan == 0) {
#pragma unroll
        for (int r = 0; r < 4; ++r)
            scores[b * 512 + s0 + wave * 16 + lk * 4 + r] = rsum[r];
    }
}

// ---------------------------------------------------------------------------
// 4. masked softmax (detects bool storage layout)
__global__ __launch_bounds__(256) void k_softmax(const float* __restrict__ scores,
                                                 const unsigned* __restrict__ mask,
                                                 float* __restrict__ w) {
    int b = blockIdx.x, tid = threadIdx.x;
    __shared__ float sv[512];
    __shared__ float rbuf[256];
    __shared__ int flag;
    int bad = 0;
    for (int i = tid; i < 512; i += 256)
        if (mask[i] > 1u) bad = 1;
    if (tid == 0) flag = 0;
    __syncthreads();
    if (bad) atomicOr(&flag, 1);
    __syncthreads();
    bool u8 = (flag != 0);
    const unsigned char* m8 = (const unsigned char*)mask;
    for (int i = tid; i < 512; i += 256) {
        bool m = u8 ? (m8[(size_t)b * 512 + i] != 0) : (mask[(size_t)b * 512 + i] != 0u);
        sv[i] = m ? scores[(size_t)b * 512 + i] : -1e9f;
    }
    __syncthreads();
    float mx = fmaxf(sv[tid], sv[tid + 256]);
    rbuf[tid] = mx;
    __syncthreads();
    for (int off = 128; off > 0; off >>= 1) {
        if (tid < off) rbuf[tid] = fmaxf(rbuf[tid], rbuf[tid + off]);
        __syncthreads();
    }
    float m = rbuf[0];
    __syncthreads();
    float e0 = expf(sv[tid] - m), e1 = expf(sv[tid + 256] - m);
    rbuf[tid] = e0 + e1;
    __syncthreads();
    for (int off = 128; off > 0; off >>= 1) {
        if (tid < off) rbuf[tid] += rbuf[tid + off];
        __syncthreads();
    }
    float inv = 1.f / rbuf[0];
    w[(size_t)b * 512 + tid]       = e0 * inv;
    w[(size_t)b * 512 + tid + 256] = e1 * inv;
}

// ---------------------------------------------------------------------------
// 5a. context partials over s-chunks of 128. grid (4, 64, 4)
__global__ __launch_bounds__(256) void k_context_part(const float* __restrict__ enc,
                                                      const float* __restrict__ w,
                                                      float* __restrict__ part) {
    int b = blockIdx.y;
    int d = blockIdx.x * 256 + threadIdx.x;
    int sc = blockIdx.z;
    __shared__ float sw[128];
    if (threadIdx.x < 128) sw[threadIdx.x] = w[(size_t)b * 512 + sc * 128 + threadIdx.x];
    __syncthreads();
    const float* e = enc + ((size_t)b * 512 + sc * 128) * 1024 + d;
    float acc = 0.f;
#pragma unroll 8
    for (int s = 0; s < 128; ++s) acc += sw[s] * e[(size_t)s * 1024];
    part[(size_t)sc * 65536 + b * 1024 + d] = acc;
}

// 5b. reduce 4 partials
__global__ __launch_bounds__(256) void k_ctx_reduce(const float* __restrict__ part,
                                                    float* __restrict__ ctx) {
    int i = blockIdx.x * 256 + threadIdx.x;
    ctx[i] = part[i] + part[65536 + i] + part[131072 + i] + part[196608 + i];
}

// ---------------------------------------------------------------------------
// 6. gates GEMM, N-tile 16 -> grid 256 (1 block/CU)
__global__ __launch_bounds__(256) void k_gates(const float* __restrict__ emb,
                                               const float* __restrict__ ctx,
                                               const float* __restrict__ h,
                                               const float* __restrict__ Wih,
                                               const float* __restrict__ Whh,
                                               float* __restrict__ gates) {
    int j0 = blockIdx.x * 16;
    __shared__ float Xs[32][68];
    __shared__ float Ws[32][20];
    int tid = threadIdx.x;
    int tx = tid & 15, ty = tid >> 4;
    float acc[4] = {0.f, 0.f, 0.f, 0.f};
    for (int k0 = 0; k0 < 2560; k0 += 32) {
        const float* xsrc; int xstride, xoff;
        if (k0 < 512)       { xsrc = emb; xstride = 512;  xoff = k0; }
        else if (k0 < 1536) { xsrc = ctx; xstride = 1024; xoff = k0 - 512; }
        else                { xsrc = h;   xstride = 1024; xoff = k0 - 1536; }
        const float* wsrc; int wstride, woff;
        if (k0 < 1536) { wsrc = Wih; wstride = 1536; woff = k0; }
        else           { wsrc = Whh; wstride = 1024; woff = k0 - 1536; }
        __syncthreads();
#pragma unroll
        for (int i = 0; i < 8; ++i) {
            int idx = tid + i * 256;
            int kk = idx & 31, bb = idx >> 5;
            Xs[kk][bb] = xsrc[(size_t)bb * xstride + xoff + kk];
        }
        {
            int idx = tid;
            int kk = idx & 31, jj = idx >> 5;
            if (jj < 16) {
                Ws[kk][jj] = wsrc[(size_t)(j0 + jj) * wstride + woff + kk];
                Ws[kk][jj + 8 < 16 ? jj : jj] = Ws[kk][jj]; // no-op keep
            }
        }
        // full Ws staging: 512 entries, 2 iters
#pragma unroll
        for (int i = 0; i < 2; ++i) {
            int idx = tid + i * 256;
            int kk = idx & 31, jj = idx >> 5;
            Ws[kk][jj] = wsrc[(size_t)(j0 + jj) * wstride + woff + kk];
        }
        __syncthreads();
#pragma unroll
        for (int kk = 0; kk < 32; ++kk) {
            float4 x4 = *(const float4*)&Xs[kk][ty * 4];
            float w0 = Ws[kk][tx];
            acc[0] += x4.x * w0;
            acc[1] += x4.y * w0;
            acc[2] += x4.z * w0;
            acc[3] += x4.w * w0;
        }
    }
#pragma unroll
    for (int ri = 0; ri < 4; ++ri) {
        int bb = ty * 4 + ri;
        gates[(size_t)bb * 4096 + j0 + tx] = acc[ri];
    }
}

// ---------------------------------------------------------------------------
// 7. LSTM elementwise
__global__ __launch_bounds__(256) void k_lstm(const float* __restrict__ gates,
                                              const float* __restrict__ bih,
                                              const float* __restrict__ bhh,
                                              const float* __restrict__ c0,
                                              float* __restrict__ out_h,
                                              float* __restrict__ out_c) {
    int idx = blockIdx.x * 256 + threadIdx.x;
    int b = idx >> 10, hh = idx & 1023;
    const float* g = gates + (size_t)b * 4096;
    float ig = g[hh]        + bih[hh]        + bhh[hh];
    float fg = g[1024 + hh] + bih[1024 + hh] + bhh[1024 + hh];
    float gg = g[2048 + hh] + bih[2048 + hh] + bhh[2048 + hh];
    float og = g[3072 + hh] + bih[3072 + hh] + bhh[3072 + hh];
    float c_old = c0[idx];
    float nc = sigmoidf_(fg) * c_old + sigmoidf_(ig) * tanhf(gg);
    float nh = sigmoidf_(og) * tanhf(nc);
    out_h[idx] = nh;
    out_c[idx] = nc;
}

// ---------------------------------------------------------------------------
// 8a. readout partials: grid (32 j-tiles of 16, 4 K-chunks of 640)
__global__ __launch_bounds__(256) void k_readout_part(const float* __restrict__ nh,
                                                      const float* __restrict__ ctx,
                                                      const float* __restrict__ emb,
                                                      const float* __restrict__ Wo,
                                                      float* __restrict__ Tp) {
    int j0 = blockIdx.x * 16;
    int kc = blockIdx.y;
    __shared__ float Xs[32][68];
    __shared__ float Ws[32][20];
    int tid = threadIdx.x;
    int tx = tid & 15, ty = tid >> 4;
    float acc[4] = {0.f, 0.f, 0.f, 0.f};
    for (int k0 = kc * 640; k0 < (kc + 1) * 640; k0 += 32) {
        const float* xsrc; int xstride, xoff;
        if (k0 < 1024)      { xsrc = nh;  xstride = 1024; xoff = k0; }
        else if (k0 < 2048) { xsrc = ctx; xstride = 1024; xoff = k0 - 1024; }
        else                { xsrc = emb; xstride = 512;  xoff = k0 - 2048; }
        __syncthreads();
#pragma unroll
        for (int i = 0; i < 8; ++i) {
            int idx = tid + i * 256;
            int kk = idx & 31, bb = idx >> 5;
            Xs[kk][bb] = xsrc[(size_t)bb * xstride + xoff + kk];
        }
#pragma unroll
        for (int i = 0; i < 2; ++i) {
            int idx = tid + i * 256;
            int kk = idx & 31, jj = idx >> 5;
            Ws[kk][jj] = Wo[(size_t)(j0 + jj) * 2560 + k0 + kk];
        }
        __syncthreads();
#pragma unroll
        for (int kk = 0; kk < 32; ++kk) {
            float4 x4 = *(const float4*)&Xs[kk][ty * 4];
            float w0 = Ws[kk][tx];
            acc[0] += x4.x * w0;
            acc[1] += x4.y * w0;
            acc[2] += x4.z * w0;
            acc[3] += x4.w * w0;
        }
    }
#pragma unroll
    for (int ri = 0; ri < 4; ++ri) {
        int bb = ty * 4 + ri;
        Tp[((size_t)kc * 64 + bb) * 512 + j0 + tx] = acc[ri];
    }
}

// 8b. readout finish: T = tanh(sum partials + bias)
__global__ __launch_bounds__(256) void k_readout_fin(const float* __restrict__ Tp,
                                                     const float* __restrict__ bo,
                                                     float* __restrict__ T) {
    int i = blockIdx.x * 256 + threadIdx.x;   // over 64*512
    int j = i & 511;
    float s = Tp[i] + Tp[32768 + i] + Tp[65536 + i] + Tp[98304 + i];
    T[i] = tanhf(s + bo[j]);
}

// ---------------------------------------------------------------------------
// 9. logits, N-tile 64 -> grid 500 (2 blocks/CU)
__global__ __launch_bounds__(256) void k_logits(const float* __restrict__ T,
                                                const float* __restrict__ table,
                                                float* __restrict__ out) {
    int j0 = blockIdx.x * 64;
    __shared__ float Ts[32][68];
    __shared__ float Es[32][68];
    int tid = threadIdx.x;
    int tx = tid & 15, ty = tid >> 4;
    float acc[4][4];
#pragma unroll
    for (int i = 0; i < 4; ++i)
#pragma unroll
        for (int j = 0; j < 4; ++j) acc[i][j] = 0.f;
    for (int k0 = 0; k0 < 512; k0 += 32) {
        __syncthreads();
#pragma unroll
        for (int i = 0; i < 8; ++i) {
            int idx = tid + i * 256;
            int kk = idx & 31, bb = idx >> 5;
            Ts[kk][bb] = T[(size_t)bb * 512 + k0 + kk];
        }
#pragma unroll
        for (int i = 0; i < 8; ++i) {
            int idx = tid + i * 256;
            int kk = idx & 31, jj = idx >> 5;
            Es[kk][jj] = table[(size_t)(j0 + jj) * 512 + k0 + kk];
        }
        __syncthreads();
#pragma unroll
        for (int kk = 0; kk < 32; ++kk) {
            float4 x4 = *(const float4*)&Ts[kk][ty * 4];
            float4 e4 = *(const float4*)&Es[kk][tx * 4];
            float xv[4] = {x4.x, x4.y, x4.z, x4.w};
            float ev[4] = {e4.x, e4.y, e4.z, e4.w};
#pragma unroll
            for (int ri = 0; ri < 4; ++ri)
#pragma unroll
                for (int cj = 0; cj < 4; ++cj) acc[ri][cj] += xv[ri] * ev[cj];
        }
    }
#pragma unroll
    for (int ri = 0; ri < 4; ++ri) {
        int bb = ty * 4 + ri;
#pragma unroll
        for (int cj = 0; cj < 4; ++cj)
            out[(size_t)bb * 32000 + j0 + tx * 4 + cj] = acc[ri][cj];
    }
}

// ---------------------------------------------------------------------------
extern "C" void kernel_launch(void* const* d_in, const int* in_sizes, int n_in,
                              void* d_out, int out_size, void* d_ws, size_t ws_size,
                              hipStream_t stream) {
    const int*      tok   = (const int*)d_in[0];
    const float*    h0    = (const float*)d_in[1];
    const float*    c0    = (const float*)d_in[2];
    const float*    enc   = (const float*)d_in[3];
    const unsigned* mask  = (const unsigned*)d_in[4];
    const float*    table = (const float*)d_in[5];
    const float*    We    = (const float*)d_in[6];
    const float*    Wd    = (const float*)d_in[7];
    const float*    va    = (const float*)d_in[8];
    const float*    Wih   = (const float*)d_in[9];
    const float*    Whh   = (const float*)d_in[10];
    const float*    bih   = (const float*)d_in[11];
    const float*    bhh   = (const float*)d_in[12];
    const float*    Wo    = (const float*)d_in[13];
    const float*    bo    = (const float*)d_in[14];

    float* out    = (float*)d_out;
    float* logits = out;                      // 64*32000
    float* out_h  = out + 2048000;            // 65536
    float* out_c  = out + 2048000 + 65536;    // 65536
    float* out_w  = out + 2048000 + 131072;   // 32768

    float* ws     = (float*)d_ws;
    float* emb    = ws;             // 32768
    float* dp     = ws + 32768;     // 16384
    float* scores = ws + 49152;     // 32768
    float* ctx    = ws + 81920;     // 65536
    float* gates  = ws + 147456;    // 262144 (aliased: ctx partials, then gates, then Tp)
    float* T      = ws + 409600;    // 32768
    ushort* Wbf   = (ushort*)(ws + 442368);   // 262144 bf16
    float* Tp     = gates;          // 131072 floats, reused after k_lstm

    k_embed       <<<64, 256, 0, stream>>>(tok, table, emb);
    k_convW       <<<256, 256, 0, stream>>>(We, Wbf);
    k_dec_proj    <<<64, 256, 0, stream>>>(h0, Wd, dp);
    k_scores_mfma <<<512, 256, 0, stream>>>(enc, Wbf, dp, va, scores);
    k_softmax     <<<64, 256, 0, stream>>>(scores, mask, out_w);
    k_context_part<<<dim3(4, 64, 4), 256, 0, stream>>>(enc, out_w, gates);
    k_ctx_reduce  <<<256, 256, 0, stream>>>(gates, ctx);
    k_gates       <<<256, 256, 0, stream>>>(emb, ctx, h0, Wih, Whh, gates);
    k_lstm        <<<256, 256, 0, stream>>>(gates, bih, bhh, c0, out_h, out_c);
    k_readout_part<<<dim3(32, 4), 256, 0, stream>>>(out_h, ctx, emb, Wo, Tp);
    k_readout_fin <<<128, 256, 0, stream>>>(Tp, bo, T);
    k_logits      <<<500, 256, 0, stream>>>(T, table, logits);
}

// Round 4
// 224.881 us; speedup vs baseline: 3.8771x; 1.1950x over previous
//
#include <hip/hip_runtime.h>
#include <hip/hip_bf16.h>
#include <math.h>

// B=64, S=512, VOCAB=32000, EMBED=512, HIDDEN=1024, ENC=1024, ATTN=256

typedef float f32x4 __attribute__((ext_vector_type(4)));
typedef short s16x8 __attribute__((ext_vector_type(8)));

__device__ __forceinline__ float sigmoidf_(float x) { return 1.0f / (1.0f + expf(-x)); }

__device__ __forceinline__ ushort f2bf(float f) {
    __hip_bfloat16 h = __float2bfloat16(f);
    return *reinterpret_cast<ushort*>(&h);
}

// ---------------------------------------------------------------------------
// 1. Embedding gather
__global__ __launch_bounds__(256) void k_embed(const int* __restrict__ tok,
                                               const float* __restrict__ table,
                                               float* __restrict__ emb) {
    int b = blockIdx.x;
    int t = tok[b];
    const float4* src = (const float4*)(table + (size_t)t * 512);
    float4* dst = (float4*)(emb + (size_t)b * 512);
    for (int i = threadIdx.x; i < 128; i += 256) dst[i] = src[i];
}

// ---------------------------------------------------------------------------
// 2. dec_proj[b][a] = sum_k h[b][k] * Wd[a][k]
__global__ __launch_bounds__(256) void k_dec_proj(const float* __restrict__ h,
                                                  const float* __restrict__ Wd,
                                                  float* __restrict__ dp) {
    int b = blockIdx.x;
    int a = threadIdx.x;
    __shared__ float sh[1024];
    for (int i = threadIdx.x; i < 1024; i += 256) sh[i] = h[(size_t)b * 1024 + i];
    __syncthreads();
    const float* w = Wd + (size_t)a * 1024;
    float acc = 0.f;
#pragma unroll 4
    for (int k = 0; k < 1024; k += 4) {
        float4 w4 = *(const float4*)(w + k);
        float4 h4 = *(const float4*)(sh + k);
        acc += w4.x * h4.x + w4.y * h4.y + w4.z * h4.z + w4.w * h4.w;
    }
    dp[b * 256 + a] = acc;
}

// ---------------------------------------------------------------------------
// 2b. Convert We [256][1024] f32 -> bf16
__global__ __launch_bounds__(256) void k_convW(const float* __restrict__ W,
                                               ushort* __restrict__ Wb) {
    int i = blockIdx.x * 256 + threadIdx.x;
    float4 f = ((const float4*)W)[i];
    ushort4 o;
    o.x = f2bf(f.x); o.y = f2bf(f.y); o.z = f2bf(f.z); o.w = f2bf(f.w);
    ((ushort4*)Wb)[i] = o;
}

// ---------------------------------------------------------------------------
// 3. scores via MFMA, LDS-staged (XOR-swizzled slots)
__global__ __launch_bounds__(256, 3) void k_scores_mfma(const float* __restrict__ enc,
                                                        const ushort* __restrict__ Wbf,
                                                        const float* __restrict__ dp,
                                                        const float* __restrict__ v,
                                                        float* __restrict__ scores) {
    int b  = blockIdx.x >> 3;
    int s0 = (blockIdx.x & 7) << 6;
    int tid = threadIdx.x;
    int wave = tid >> 6, lane = tid & 63;
    int lan = lane & 15, lk = lane >> 4;

    __shared__ s16x8 Al[512];    // 64 rows x 8 koct
    __shared__ s16x8 Bl[2048];   // 256 a  x 8 koct
    __shared__ float sdp[256], sv[256];

    sdp[tid] = dp[b * 256 + tid];
    sv[tid]  = v[tid];

    const float* encB = enc + ((size_t)(b * 512 + s0)) * 1024;

    f32x4 acc[16];
#pragma unroll
    for (int ni = 0; ni < 16; ++ni) acc[ni] = (f32x4){0.f, 0.f, 0.f, 0.f};

    for (int k0 = 0; k0 < 1024; k0 += 64) {
        __syncthreads();
#pragma unroll
        for (int it = 0; it < 2; ++it) {
            int idx = tid + it * 256;
            int row = idx >> 3, koct = idx & 7;
            const float* src = encB + (size_t)row * 1024 + k0 + koct * 8;
            float4 f0 = *(const float4*)src;
            float4 f1 = *(const float4*)(src + 4);
            s16x8 pk;
            pk[0] = (short)f2bf(f0.x); pk[1] = (short)f2bf(f0.y);
            pk[2] = (short)f2bf(f0.z); pk[3] = (short)f2bf(f0.w);
            pk[4] = (short)f2bf(f1.x); pk[5] = (short)f2bf(f1.y);
            pk[6] = (short)f2bf(f1.z); pk[7] = (short)f2bf(f1.w);
            Al[row * 8 + (koct ^ (row & 7))] = pk;
        }
#pragma unroll
        for (int it = 0; it < 8; ++it) {
            int idx = tid + it * 256;
            int a = idx >> 3, koct = idx & 7;
            s16x8 wv = *(const s16x8*)(Wbf + (size_t)a * 1024 + k0 + koct * 8);
            Bl[a * 8 + (koct ^ (a & 7))] = wv;
        }
        __syncthreads();
#pragma unroll
        for (int ks = 0; ks < 2; ++ks) {
            int arow = wave * 16 + lan;
            int akoct = ks * 4 + lk;
            s16x8 af = Al[arow * 8 + (akoct ^ (arow & 7))];
#pragma unroll
            for (int ni = 0; ni < 16; ++ni) {
                int a = ni * 16 + lan;
                s16x8 bf = Bl[a * 8 + (akoct ^ (a & 7))];
                acc[ni] = __builtin_amdgcn_mfma_f32_16x16x32_bf16(af, bf, acc[ni], 0, 0, 0);
            }
        }
    }

    float rsum[4] = {0.f, 0.f, 0.f, 0.f};
#pragma unroll
    for (int ni = 0; ni < 16; ++ni) {
        int a = ni * 16 + lan;
        float dpv = sdp[a], vv = sv[a];
#pragma unroll
        for (int r = 0; r < 4; ++r) {
            float x = acc[ni][r] + dpv;
            float t = 1.f - 2.f / (1.f + __expf(2.f * x));   // tanh
            rsum[r] += t * vv;
        }
    }
#pragma unroll
    for (int off = 1; off < 16; off <<= 1) {
#pragma unroll
        for (int r = 0; r < 4; ++r) rsum[r] += __shfl_xor(rsum[r], off);
    }
    if (lan == 0) {
#pragma unroll
        for (int r = 0; r < 4; ++r)
            scores[b * 512 + s0 + wave * 16 + lk * 4 + r] = rsum[r];
    }
}

// ---------------------------------------------------------------------------
// 4. masked softmax (detects bool storage layout)
__global__ __launch_bounds__(256) void k_softmax(const float* __restrict__ scores,
                                                 const unsigned* __restrict__ mask,
                                                 float* __restrict__ w) {
    int b = blockIdx.x, tid = threadIdx.x;
    __shared__ float sv[512];
    __shared__ float rbuf[256];
    __shared__ int flag;
    int bad = 0;
    for (int i = tid; i < 512; i += 256)
        if (mask[i] > 1u) bad = 1;
    if (tid == 0) flag = 0;
    __syncthreads();
    if (bad) atomicOr(&flag, 1);
    __syncthreads();
    bool u8 = (flag != 0);
    const unsigned char* m8 = (const unsigned char*)mask;
    for (int i = tid; i < 512; i += 256) {
        bool m = u8 ? (m8[(size_t)b * 512 + i] != 0) : (mask[(size_t)b * 512 + i] != 0u);
        sv[i] = m ? scores[(size_t)b * 512 + i] : -1e9f;
    }
    __syncthreads();
    float mx = fmaxf(sv[tid], sv[tid + 256]);
    rbuf[tid] = mx;
    __syncthreads();
    for (int off = 128; off > 0; off >>= 1) {
        if (tid < off) rbuf[tid] = fmaxf(rbuf[tid], rbuf[tid + off]);
        __syncthreads();
    }
    float m = rbuf[0];
    __syncthreads();
    float e0 = expf(sv[tid] - m), e1 = expf(sv[tid + 256] - m);
    rbuf[tid] = e0 + e1;
    __syncthreads();
    for (int off = 128; off > 0; off >>= 1) {
        if (tid < off) rbuf[tid] += rbuf[tid + off];
        __syncthreads();
    }
    float inv = 1.f / rbuf[0];
    w[(size_t)b * 512 + tid]       = e0 * inv;
    w[(size_t)b * 512 + tid + 256] = e1 * inv;
}

// ---------------------------------------------------------------------------
// 5a. context partials over s-chunks of 128. grid (4, 64, 4)
__global__ __launch_bounds__(256) void k_context_part(const float* __restrict__ enc,
                                                      const float* __restrict__ w,
                                                      float* __restrict__ part) {
    int b = blockIdx.y;
    int d = blockIdx.x * 256 + threadIdx.x;
    int sc = blockIdx.z;
    __shared__ float sw[128];
    if (threadIdx.x < 128) sw[threadIdx.x] = w[(size_t)b * 512 + sc * 128 + threadIdx.x];
    __syncthreads();
    const float* e = enc + ((size_t)b * 512 + sc * 128) * 1024 + d;
    float acc = 0.f;
#pragma unroll 8
    for (int s = 0; s < 128; ++s) acc += sw[s] * e[(size_t)s * 1024];
    part[(size_t)sc * 65536 + b * 1024 + d] = acc;
}

// 5b. reduce 4 partials
__global__ __launch_bounds__(256) void k_ctx_reduce(const float* __restrict__ part,
                                                    float* __restrict__ ctx) {
    int i = blockIdx.x * 256 + threadIdx.x;
    ctx[i] = part[i] + part[65536 + i] + part[131072 + i] + part[196608 + i];
}

// ---------------------------------------------------------------------------
// 6. gates partial GEMM. grid (64 j-tiles of 64, 8 K-chunks of 320).
//    Thread tile 4b x 4j. LDS row-major-with-pad [.][33]: staging writes
//    sequential, compute reads <=2-way. Partials: kc<7 -> p0 (logits region),
//    kc==7 -> p7 (ws).
__global__ __launch_bounds__(256) void k_gates_part(const float* __restrict__ emb,
                                                    const float* __restrict__ ctx,
                                                    const float* __restrict__ h,
                                                    const float* __restrict__ Wih,
                                                    const float* __restrict__ Whh,
                                                    float* __restrict__ p0,
                                                    float* __restrict__ p7) {
    int j0 = blockIdx.x * 64;
    int kc = blockIdx.y;
    __shared__ float Xs[64][33];
    __shared__ float Ws[64][33];
    int tid = threadIdx.x;
    int tx = tid & 15, ty = tid >> 4;
    float acc[4][4];
#pragma unroll
    for (int i = 0; i < 4; ++i)
#pragma unroll
        for (int j = 0; j < 4; ++j) acc[i][j] = 0.f;

    for (int k0 = kc * 320; k0 < kc * 320 + 320; k0 += 32) {
        const float* xsrc; int xstride, xoff;
        if (k0 < 512)       { xsrc = emb; xstride = 512;  xoff = k0; }
        else if (k0 < 1536) { xsrc = ctx; xstride = 1024; xoff = k0 - 512; }
        else                { xsrc = h;   xstride = 1024; xoff = k0 - 1536; }
        const float* wsrc; int wstride, woff;
        if (k0 < 1536) { wsrc = Wih; wstride = 1536; woff = k0; }
        else           { wsrc = Whh; wstride = 1024; woff = k0 - 1536; }
        __syncthreads();
#pragma unroll
        for (int i = 0; i < 8; ++i) {
            int idx = tid + i * 256;
            int kk = idx & 31, bb = idx >> 5;
            Xs[bb][kk] = xsrc[(size_t)bb * xstride + xoff + kk];
        }
#pragma unroll
        for (int i = 0; i < 8; ++i) {
            int idx = tid + i * 256;
            int kk = idx & 31, jj = idx >> 5;
            Ws[jj][kk] = wsrc[(size_t)(j0 + jj) * wstride + woff + kk];
        }
        __syncthreads();
#pragma unroll
        for (int kk = 0; kk < 32; ++kk) {
            float x0 = Xs[ty * 4 + 0][kk];
            float x1 = Xs[ty * 4 + 1][kk];
            float x2 = Xs[ty * 4 + 2][kk];
            float x3 = Xs[ty * 4 + 3][kk];
            float w0 = Ws[tx * 4 + 0][kk];
            float w1 = Ws[tx * 4 + 1][kk];
            float w2 = Ws[tx * 4 + 2][kk];
            float w3 = Ws[tx * 4 + 3][kk];
            acc[0][0] += x0 * w0; acc[0][1] += x0 * w1; acc[0][2] += x0 * w2; acc[0][3] += x0 * w3;
            acc[1][0] += x1 * w0; acc[1][1] += x1 * w1; acc[1][2] += x1 * w2; acc[1][3] += x1 * w3;
            acc[2][0] += x2 * w0; acc[2][1] += x2 * w1; acc[2][2] += x2 * w2; acc[2][3] += x2 * w3;
            acc[3][0] += x3 * w0; acc[3][1] += x3 * w1; acc[3][2] += x3 * w2; acc[3][3] += x3 * w3;
        }
    }
    float* dst = (kc < 7) ? (p0 + (size_t)kc * 262144) : p7;
#pragma unroll
    for (int ri = 0; ri < 4; ++ri) {
        int bb = ty * 4 + ri;
#pragma unroll
        for (int cj = 0; cj < 4; ++cj)
            dst[(size_t)bb * 4096 + j0 + tx * 4 + cj] = acc[ri][cj];
    }
}

// ---------------------------------------------------------------------------
// 7. LSTM elementwise + 8-way partial reduce
__global__ __launch_bounds__(256) void k_lstm(const float* __restrict__ p0,
                                              const float* __restrict__ p7,
                                              const float* __restrict__ bih,
                                              const float* __restrict__ bhh,
                                              const float* __restrict__ c0,
                                              float* __restrict__ out_h,
                                              float* __restrict__ out_c) {
    int idx = blockIdx.x * 256 + threadIdx.x;
    int b = idx >> 10, hh = idx & 1023;
    float g[4];
#pragma unroll
    for (int gt = 0; gt < 4; ++gt) {
        size_t off = (size_t)b * 4096 + gt * 1024 + hh;
        float s = p7[off] + bih[gt * 1024 + hh] + bhh[gt * 1024 + hh];
#pragma unroll
        for (int kc = 0; kc < 7; ++kc) s += p0[(size_t)kc * 262144 + off];
        g[gt] = s;
    }
    float c_old = c0[idx];
    float nc = sigmoidf_(g[1]) * c_old + sigmoidf_(g[0]) * tanhf(g[2]);
    float nh = sigmoidf_(g[3]) * tanhf(nc);
    out_h[idx] = nh;
    out_c[idx] = nc;
}

// ---------------------------------------------------------------------------
// 8a. readout partials: grid (32 j-tiles of 16, 16 K-chunks of 160).
//     Thread: b = tid&63 (one b per lane), jg = wave (4 j per thread).
__global__ __launch_bounds__(256) void k_readout_part(const float* __restrict__ nh,
                                                      const float* __restrict__ ctx,
                                                      const float* __restrict__ emb,
                                                      const float* __restrict__ Wo,
                                                      float* __restrict__ Tp) {
    int j0 = blockIdx.x * 16;
    int kc = blockIdx.y;
    __shared__ float Xs[64][33];
    __shared__ float Ws[16][33];
    int tid = threadIdx.x;
    int b = tid & 63, jg = tid >> 6;
    float acc[4] = {0.f, 0.f, 0.f, 0.f};

    for (int k0 = kc * 160; k0 < kc * 160 + 160; k0 += 32) {
        const float* xsrc; int xstride, xoff;
        if (k0 < 1024)      { xsrc = nh;  xstride = 1024; xoff = k0; }
        else if (k0 < 2048) { xsrc = ctx; xstride = 1024; xoff = k0 - 1024; }
        else                { xsrc = emb; xstride = 512;  xoff = k0 - 2048; }
        __syncthreads();
#pragma unroll
        for (int i = 0; i < 8; ++i) {
            int idx = tid + i * 256;
            int kk = idx & 31, bb = idx >> 5;
            Xs[bb][kk] = xsrc[(size_t)bb * xstride + xoff + kk];
        }
#pragma unroll
        for (int i = 0; i < 2; ++i) {
            int idx = tid + i * 256;
            int kk = idx & 31, jj = idx >> 5;
            Ws[jj][kk] = Wo[(size_t)(j0 + jj) * 2560 + k0 + kk];
        }
        __syncthreads();
#pragma unroll
        for (int kk = 0; kk < 32; ++kk) {
            float x = Xs[b][kk];
            acc[0] += x * Ws[jg * 4 + 0][kk];
            acc[1] += x * Ws[jg * 4 + 1][kk];
            acc[2] += x * Ws[jg * 4 + 2][kk];
            acc[3] += x * Ws[jg * 4 + 3][kk];
        }
    }
#pragma unroll
    for (int c = 0; c < 4; ++c)
        Tp[((size_t)kc * 64 + b) * 512 + j0 + jg * 4 + c] = acc[c];
}

// 8b. readout finish: T = tanh(sum 16 partials + bias)
__global__ __launch_bounds__(256) void k_readout_fin(const float* __restrict__ Tp,
                                                     const float* __restrict__ bo,
                                                     float* __restrict__ T) {
    int i = blockIdx.x * 256 + threadIdx.x;   // over 64*512
    int j = i & 511;
    float s = 0.f;
#pragma unroll
    for (int kc = 0; kc < 16; ++kc) s += Tp[(size_t)kc * 32768 + i];
    T[i] = tanhf(s + bo[j]);
}

// ---------------------------------------------------------------------------
// 9. logits, j-tile 64 -> grid 500. Thread tile 4b x 4j, LDS [64][33].
__global__ __launch_bounds__(256) void k_logits(const float* __restrict__ T,
                                                const float* __restrict__ table,
                                                float* __restrict__ out) {
    int j0 = blockIdx.x * 64;
    __shared__ float Ts[64][33];
    __shared__ float Es[64][33];
    int tid = threadIdx.x;
    int tx = tid & 15, ty = tid >> 4;
    float acc[4][4];
#pragma unroll
    for (int i = 0; i < 4; ++i)
#pragma unroll
        for (int j = 0; j < 4; ++j) acc[i][j] = 0.f;
    for (int k0 = 0; k0 < 512; k0 += 32) {
        __syncthreads();
#pragma unroll
        for (int i = 0; i < 8; ++i) {
            int idx = tid + i * 256;
            int kk = idx & 31, bb = idx >> 5;
            Ts[bb][kk] = T[(size_t)bb * 512 + k0 + kk];
        }
#pragma unroll
        for (int i = 0; i < 8; ++i) {
            int idx = tid + i * 256;
            int kk = idx & 31, jj = idx >> 5;
            Es[jj][kk] = table[(size_t)(j0 + jj) * 512 + k0 + kk];
        }
        __syncthreads();
#pragma unroll
        for (int kk = 0; kk < 32; ++kk) {
            float x0 = Ts[ty * 4 + 0][kk];
            float x1 = Ts[ty * 4 + 1][kk];
            float x2 = Ts[ty * 4 + 2][kk];
            float x3 = Ts[ty * 4 + 3][kk];
            float e0 = Es[tx * 4 + 0][kk];
            float e1 = Es[tx * 4 + 1][kk];
            float e2 = Es[tx * 4 + 2][kk];
            float e3 = Es[tx * 4 + 3][kk];
            acc[0][0] += x0 * e0; acc[0][1] += x0 * e1; acc[0][2] += x0 * e2; acc[0][3] += x0 * e3;
            acc[1][0] += x1 * e0; acc[1][1] += x1 * e1; acc[1][2] += x1 * e2; acc[1][3] += x1 * e3;
            acc[2][0] += x2 * e0; acc[2][1] += x2 * e1; acc[2][2] += x2 * e2; acc[2][3] += x2 * e3;
            acc[3][0] += x3 * e0; acc[3][1] += x3 * e1; acc[3][2] += x3 * e2; acc[3][3] += x3 * e3;
        }
    }
#pragma unroll
    for (int ri = 0; ri < 4; ++ri) {
        int bb = ty * 4 + ri;
#pragma unroll
        for (int cj = 0; cj < 4; ++cj)
            out[(size_t)bb * 32000 + j0 + tx * 4 + cj] = acc[ri][cj];
    }
}

// ---------------------------------------------------------------------------
extern "C" void kernel_launch(void* const* d_in, const int* in_sizes, int n_in,
                              void* d_out, int out_size, void* d_ws, size_t ws_size,
                              hipStream_t stream) {
    const int*      tok   = (const int*)d_in[0];
    const float*    h0    = (const float*)d_in[1];
    const float*    c0    = (const float*)d_in[2];
    const float*    enc   = (const float*)d_in[3];
    const unsigned* mask  = (const unsigned*)d_in[4];
    const float*    table = (const float*)d_in[5];
    const float*    We    = (const float*)d_in[6];
    const float*    Wd    = (const float*)d_in[7];
    const float*    va    = (const float*)d_in[8];
    const float*    Wih   = (const float*)d_in[9];
    const float*    Whh   = (const float*)d_in[10];
    const float*    bih   = (const float*)d_in[11];
    const float*    bhh   = (const float*)d_in[12];
    const float*    Wo    = (const float*)d_in[13];
    const float*    bo    = (const float*)d_in[14];

    float* out    = (float*)d_out;
    float* logits = out;                      // 64*32000 = 2048000
    float* out_h  = out + 2048000;            // 65536
    float* out_c  = out + 2048000 + 65536;    // 65536
    float* out_w  = out + 2048000 + 131072;   // 32768

    float* ws     = (float*)d_ws;
    float* emb    = ws;             // 32768
    float* dp     = ws + 32768;     // 16384
    float* scores = ws + 49152;     // 32768
    float* ctx    = ws + 81920;     // 65536
    float* big    = ws + 147456;    // 524288 floats scratch (ctx partials / gates p7 / readout Tp)
    float* T      = ws + 671744;    // 32768
    ushort* Wbf   = (ushort*)(ws + 704512);   // 262144 bf16 (131072 float-slots)

    float* gates_p0 = logits;       // kc 0..6 partials (7*262144 <= 2048000), overwritten by k_logits
    float* gates_p7 = big;          // kc 7 partial
    float* Tp       = big;          // readout partials (after k_lstm consumed gates)

    k_embed       <<<64, 256, 0, stream>>>(tok, table, emb);
    k_convW       <<<256, 256, 0, stream>>>(We, Wbf);
    k_dec_proj    <<<64, 256, 0, stream>>>(h0, Wd, dp);
    k_scores_mfma <<<512, 256, 0, stream>>>(enc, Wbf, dp, va, scores);
    k_softmax     <<<64, 256, 0, stream>>>(scores, mask, out_w);
    k_context_part<<<dim3(4, 64, 4), 256, 0, stream>>>(enc, out_w, big);
    k_ctx_reduce  <<<256, 256, 0, stream>>>(big, ctx);
    k_gates_part  <<<dim3(64, 8), 256, 0, stream>>>(emb, ctx, h0, Wih, Whh, gates_p0, gates_p7);
    k_lstm        <<<256, 256, 0, stream>>>(gates_p0, gates_p7, bih, bhh, c0, out_h, out_c);
    k_readout_part<<<dim3(32, 16), 256, 0, stream>>>(out_h, ctx, emb, Wo, Tp);
    k_readout_fin <<<128, 256, 0, stream>>>(Tp, bo, T);
    k_logits      <<<500, 256, 0, stream>>>(T, table, logits);
}

// Round 5
// 214.460 us; speedup vs baseline: 4.0655x; 1.0486x over previous
//
#include <hip/hip_runtime.h>
#include <hip/hip_bf16.h>
#include <math.h>

// B=64, S=512, VOCAB=32000, EMBED=512, HIDDEN=1024, ENC=1024, ATTN=256

typedef float f32x4 __attribute__((ext_vector_type(4)));
typedef short s16x8 __attribute__((ext_vector_type(8)));

__device__ __forceinline__ float sigmoidf_(float x) { return 1.0f / (1.0f + expf(-x)); }

__device__ __forceinline__ ushort f2bf(float f) {
    __hip_bfloat16 h = __float2bfloat16(f);
    return *reinterpret_cast<ushort*>(&h);
}

// ---------------------------------------------------------------------------
// 1. prep: blocks 0..63 embed gather | 64..319 We->bf16 | 320..383 dec_proj
__global__ __launch_bounds__(256) void k_prep(const int* __restrict__ tok,
                                              const float* __restrict__ table,
                                              const float* __restrict__ We,
                                              const float* __restrict__ h0,
                                              const float* __restrict__ Wd,
                                              float* __restrict__ emb,
                                              ushort* __restrict__ Wbf,
                                              float* __restrict__ dp) {
    __shared__ float sh[1024];
    int bx = blockIdx.x;
    int tid = threadIdx.x;
    if (bx < 64) {
        int b = bx;
        int t = tok[b];
        const float4* src = (const float4*)(table + (size_t)t * 512);
        float4* dst = (float4*)(emb + (size_t)b * 512);
        if (tid < 128) dst[tid] = src[tid];
    } else if (bx < 320) {
        int i = (bx - 64) * 256 + tid;
        float4 f = ((const float4*)We)[i];
        ushort4 o;
        o.x = f2bf(f.x); o.y = f2bf(f.y); o.z = f2bf(f.z); o.w = f2bf(f.w);
        ((ushort4*)Wbf)[i] = o;
    } else {
        int b = bx - 320;
        int a = tid;
        for (int i = tid; i < 1024; i += 256) sh[i] = h0[(size_t)b * 1024 + i];
        __syncthreads();
        const float* w = Wd + (size_t)a * 1024;
        float acc = 0.f;
#pragma unroll 4
        for (int k = 0; k < 1024; k += 4) {
            float4 w4 = *(const float4*)(w + k);
            float4 h4 = *(const float4*)(sh + k);
            acc += w4.x * h4.x + w4.y * h4.y + w4.z * h4.z + w4.w * h4.w;
        }
        dp[b * 256 + a] = acc;
    }
}

// ---------------------------------------------------------------------------
// 2. scores via MFMA, LDS-staged (XOR-swizzled slots)
__global__ __launch_bounds__(256, 3) void k_scores_mfma(const float* __restrict__ enc,
                                                        const ushort* __restrict__ Wbf,
                                                        const float* __restrict__ dp,
                                                        const float* __restrict__ v,
                                                        float* __restrict__ scores) {
    int b  = blockIdx.x >> 3;
    int s0 = (blockIdx.x & 7) << 6;
    int tid = threadIdx.x;
    int wave = tid >> 6, lane = tid & 63;
    int lan = lane & 15, lk = lane >> 4;

    __shared__ s16x8 Al[512];    // 64 rows x 8 koct
    __shared__ s16x8 Bl[2048];   // 256 a  x 8 koct
    __shared__ float sdp[256], sv[256];

    sdp[tid] = dp[b * 256 + tid];
    sv[tid]  = v[tid];

    const float* encB = enc + ((size_t)(b * 512 + s0)) * 1024;

    f32x4 acc[16];
#pragma unroll
    for (int ni = 0; ni < 16; ++ni) acc[ni] = (f32x4){0.f, 0.f, 0.f, 0.f};

    for (int k0 = 0; k0 < 1024; k0 += 64) {
        __syncthreads();
#pragma unroll
        for (int it = 0; it < 2; ++it) {
            int idx = tid + it * 256;
            int row = idx >> 3, koct = idx & 7;
            const float* src = encB + (size_t)row * 1024 + k0 + koct * 8;
            float4 f0 = *(const float4*)src;
            float4 f1 = *(const float4*)(src + 4);
            s16x8 pk;
            pk[0] = (short)f2bf(f0.x); pk[1] = (short)f2bf(f0.y);
            pk[2] = (short)f2bf(f0.z); pk[3] = (short)f2bf(f0.w);
            pk[4] = (short)f2bf(f1.x); pk[5] = (short)f2bf(f1.y);
            pk[6] = (short)f2bf(f1.z); pk[7] = (short)f2bf(f1.w);
            Al[row * 8 + (koct ^ (row & 7))] = pk;
        }
#pragma unroll
        for (int it = 0; it < 8; ++it) {
            int idx = tid + it * 256;
            int a = idx >> 3, koct = idx & 7;
            s16x8 wv = *(const s16x8*)(Wbf + (size_t)a * 1024 + k0 + koct * 8);
            Bl[a * 8 + (koct ^ (a & 7))] = wv;
        }
        __syncthreads();
#pragma unroll
        for (int ks = 0; ks < 2; ++ks) {
            int arow = wave * 16 + lan;
            int akoct = ks * 4 + lk;
            s16x8 af = Al[arow * 8 + (akoct ^ (arow & 7))];
#pragma unroll
            for (int ni = 0; ni < 16; ++ni) {
                int a = ni * 16 + lan;
                s16x8 bf = Bl[a * 8 + (akoct ^ (a & 7))];
                acc[ni] = __builtin_amdgcn_mfma_f32_16x16x32_bf16(af, bf, acc[ni], 0, 0, 0);
            }
        }
    }

    float rsum[4] = {0.f, 0.f, 0.f, 0.f};
#pragma unroll
    for (int ni = 0; ni < 16; ++ni) {
        int a = ni * 16 + lan;
        float dpv = sdp[a], vv = sv[a];
#pragma unroll
        for (int r = 0; r < 4; ++r) {
            float x = acc[ni][r] + dpv;
            float t = 1.f - 2.f / (1.f + __expf(2.f * x));   // tanh
            rsum[r] += t * vv;
        }
    }
#pragma unroll
    for (int off = 1; off < 16; off <<= 1) {
#pragma unroll
        for (int r = 0; r < 4; ++r) rsum[r] += __shfl_xor(rsum[r], off);
    }
    if (lan == 0) {
#pragma unroll
        for (int r = 0; r < 4; ++r)
            scores[b * 512 + s0 + wave * 16 + lk * 4 + r] = rsum[r];
    }
}

// ---------------------------------------------------------------------------
// 3. fused softmax + context. grid (8, 64): b = y, 128-d chunk = x.
//    Each block computes the row softmax in-LDS (redundant, cheap); block x==0
//    writes out_w; all blocks then stream their enc d-chunk (L3-warm).
__global__ __launch_bounds__(256) void k_ctx(const float* __restrict__ scores,
                                             const unsigned* __restrict__ mask,
                                             const float* __restrict__ enc,
                                             float* __restrict__ out_w,
                                             float* __restrict__ ctx) {
    int b = blockIdx.y;
    int dchunk = blockIdx.x;
    int tid = threadIdx.x;
    __shared__ float sw[512];
    __shared__ float red[2][128];
    __shared__ float wred[4], sred[4];
    __shared__ int flag;

    int bad = 0;
    for (int i = tid; i < 512; i += 256)
        if (mask[i] > 1u) bad = 1;
    if (tid == 0) flag = 0;
    __syncthreads();
    if (bad) atomicOr(&flag, 1);
    __syncthreads();
    bool u8 = (flag != 0);
    const unsigned char* m8 = (const unsigned char*)mask;

    {
        bool m0 = u8 ? (m8[(size_t)b * 512 + tid] != 0)       : (mask[(size_t)b * 512 + tid] != 0u);
        bool m1 = u8 ? (m8[(size_t)b * 512 + tid + 256] != 0) : (mask[(size_t)b * 512 + tid + 256] != 0u);
        sw[tid]       = m0 ? scores[(size_t)b * 512 + tid]       : -1e9f;
        sw[tid + 256] = m1 ? scores[(size_t)b * 512 + tid + 256] : -1e9f;
    }
    __syncthreads();
    float mx = fmaxf(sw[tid], sw[tid + 256]);
#pragma unroll
    for (int off = 32; off; off >>= 1) mx = fmaxf(mx, __shfl_xor(mx, off));
    if ((tid & 63) == 0) wred[tid >> 6] = mx;
    __syncthreads();
    float m = fmaxf(fmaxf(wred[0], wred[1]), fmaxf(wred[2], wred[3]));
    float e0 = __expf(sw[tid] - m), e1 = __expf(sw[tid + 256] - m);
    float sum = e0 + e1;
#pragma unroll
    for (int off = 32; off; off >>= 1) sum += __shfl_xor(sum, off);
    if ((tid & 63) == 0) sred[tid >> 6] = sum;
    __syncthreads();
    float inv = 1.f / (sred[0] + sred[1] + sred[2] + sred[3]);
    e0 *= inv; e1 *= inv;
    __syncthreads();
    sw[tid] = e0; sw[tid + 256] = e1;
    if (dchunk == 0) {
        out_w[(size_t)b * 512 + tid]       = e0;
        out_w[(size_t)b * 512 + tid + 256] = e1;
    }
    __syncthreads();

    // context: d = dchunk*128 + (tid&127); s-half = tid>>7
    int dl = tid & 127;
    int shf = tid >> 7;
    int d = dchunk * 128 + dl;
    const float* e = enc + ((size_t)b * 512 + shf * 256) * 1024 + d;
    const float* wv = &sw[shf * 256];
    float acc = 0.f;
#pragma unroll 8
    for (int s = 0; s < 256; ++s) acc += wv[s] * e[(size_t)s * 1024];
    red[shf][dl] = acc;
    __syncthreads();
    if (tid < 128) ctx[(size_t)b * 1024 + dchunk * 128 + tid] = red[0][tid] + red[1][tid];
}

// ---------------------------------------------------------------------------
// 4. gates partial GEMM. grid (64 j-tiles of 64, 8 K-chunks of 320).
__global__ __launch_bounds__(256) void k_gates_part(const float* __restrict__ emb,
                                                    const float* __restrict__ ctx,
                                                    const float* __restrict__ h,
                                                    const float* __restrict__ Wih,
                                                    const float* __restrict__ Whh,
                                                    float* __restrict__ p0,
                                                    float* __restrict__ p7) {
    int j0 = blockIdx.x * 64;
    int kc = blockIdx.y;
    __shared__ float Xs[64][33];
    __shared__ float Ws[64][33];
    int tid = threadIdx.x;
    int tx = tid & 15, ty = tid >> 4;
    float acc[4][4];
#pragma unroll
    for (int i = 0; i < 4; ++i)
#pragma unroll
        for (int j = 0; j < 4; ++j) acc[i][j] = 0.f;

    for (int k0 = kc * 320; k0 < kc * 320 + 320; k0 += 32) {
        const float* xsrc; int xstride, xoff;
        if (k0 < 512)       { xsrc = emb; xstride = 512;  xoff = k0; }
        else if (k0 < 1536) { xsrc = ctx; xstride = 1024; xoff = k0 - 512; }
        else                { xsrc = h;   xstride = 1024; xoff = k0 - 1536; }
        const float* wsrc; int wstride, woff;
        if (k0 < 1536) { wsrc = Wih; wstride = 1536; woff = k0; }
        else           { wsrc = Whh; wstride = 1024; woff = k0 - 1536; }
        __syncthreads();
#pragma unroll
        for (int i = 0; i < 8; ++i) {
            int idx = tid + i * 256;
            int kk = idx & 31, bb = idx >> 5;
            Xs[bb][kk] = xsrc[(size_t)bb * xstride + xoff + kk];
        }
#pragma unroll
        for (int i = 0; i < 8; ++i) {
            int idx = tid + i * 256;
            int kk = idx & 31, jj = idx >> 5;
            Ws[jj][kk] = wsrc[(size_t)(j0 + jj) * wstride + woff + kk];
        }
        __syncthreads();
#pragma unroll
        for (int kk = 0; kk < 32; ++kk) {
            float x0 = Xs[ty * 4 + 0][kk];
            float x1 = Xs[ty * 4 + 1][kk];
            float x2 = Xs[ty * 4 + 2][kk];
            float x3 = Xs[ty * 4 + 3][kk];
            float w0 = Ws[tx * 4 + 0][kk];
            float w1 = Ws[tx * 4 + 1][kk];
            float w2 = Ws[tx * 4 + 2][kk];
            float w3 = Ws[tx * 4 + 3][kk];
            acc[0][0] += x0 * w0; acc[0][1] += x0 * w1; acc[0][2] += x0 * w2; acc[0][3] += x0 * w3;
            acc[1][0] += x1 * w0; acc[1][1] += x1 * w1; acc[1][2] += x1 * w2; acc[1][3] += x1 * w3;
            acc[2][0] += x2 * w0; acc[2][1] += x2 * w1; acc[2][2] += x2 * w2; acc[2][3] += x2 * w3;
            acc[3][0] += x3 * w0; acc[3][1] += x3 * w1; acc[3][2] += x3 * w2; acc[3][3] += x3 * w3;
        }
    }
    float* dst = (kc < 7) ? (p0 + (size_t)kc * 262144) : p7;
#pragma unroll
    for (int ri = 0; ri < 4; ++ri) {
        int bb = ty * 4 + ri;
#pragma unroll
        for (int cj = 0; cj < 4; ++cj)
            dst[(size_t)bb * 4096 + j0 + tx * 4 + cj] = acc[ri][cj];
    }
}

// ---------------------------------------------------------------------------
// 5. LSTM elementwise + 8-way partial reduce
__global__ __launch_bounds__(256) void k_lstm(const float* __restrict__ p0,
                                              const float* __restrict__ p7,
                                              const float* __restrict__ bih,
                                              const float* __restrict__ bhh,
                                              const float* __restrict__ c0,
                                              float* __restrict__ out_h,
                                              float* __restrict__ out_c) {
    int idx = blockIdx.x * 256 + threadIdx.x;
    int b = idx >> 10, hh = idx & 1023;
    float g[4];
#pragma unroll
    for (int gt = 0; gt < 4; ++gt) {
        size_t off = (size_t)b * 4096 + gt * 1024 + hh;
        float s = p7[off] + bih[gt * 1024 + hh] + bhh[gt * 1024 + hh];
#pragma unroll
        for (int kc = 0; kc < 7; ++kc) s += p0[(size_t)kc * 262144 + off];
        g[gt] = s;
    }
    float c_old = c0[idx];
    float nc = sigmoidf_(g[1]) * c_old + sigmoidf_(g[0]) * tanhf(g[2]);
    float nh = sigmoidf_(g[3]) * tanhf(nc);
    out_h[idx] = nh;
    out_c[idx] = nc;
}

// ---------------------------------------------------------------------------
// 6a. readout partials: grid (32 j-tiles of 16, 16 K-chunks of 160).
__global__ __launch_bounds__(256) void k_readout_part(const float* __restrict__ nh,
                                                      const float* __restrict__ ctx,
                                                      const float* __restrict__ emb,
                                                      const float* __restrict__ Wo,
                                                      float* __restrict__ Tp) {
    int j0 = blockIdx.x * 16;
    int kc = blockIdx.y;
    __shared__ float Xs[64][33];
    __shared__ float Ws[16][33];
    int tid = threadIdx.x;
    int b = tid & 63, jg = tid >> 6;
    float acc[4] = {0.f, 0.f, 0.f, 0.f};

    for (int k0 = kc * 160; k0 < kc * 160 + 160; k0 += 32) {
        const float* xsrc; int xstride, xoff;
        if (k0 < 1024)      { xsrc = nh;  xstride = 1024; xoff = k0; }
        else if (k0 < 2048) { xsrc = ctx; xstride = 1024; xoff = k0 - 1024; }
        else                { xsrc = emb; xstride = 512;  xoff = k0 - 2048; }
        __syncthreads();
#pragma unroll
        for (int i = 0; i < 8; ++i) {
            int idx = tid + i * 256;
            int kk = idx & 31, bb = idx >> 5;
            Xs[bb][kk] = xsrc[(size_t)bb * xstride + xoff + kk];
        }
#pragma unroll
        for (int i = 0; i < 2; ++i) {
            int idx = tid + i * 256;
            int kk = idx & 31, jj = idx >> 5;
            Ws[jj][kk] = Wo[(size_t)(j0 + jj) * 2560 + k0 + kk];
        }
        __syncthreads();
#pragma unroll
        for (int kk = 0; kk < 32; ++kk) {
            float x = Xs[b][kk];
            acc[0] += x * Ws[jg * 4 + 0][kk];
            acc[1] += x * Ws[jg * 4 + 1][kk];
            acc[2] += x * Ws[jg * 4 + 2][kk];
            acc[3] += x * Ws[jg * 4 + 3][kk];
        }
    }
#pragma unroll
    for (int c = 0; c < 4; ++c)
        Tp[((size_t)kc * 64 + b) * 512 + j0 + jg * 4 + c] = acc[c];
}

// 6b. readout finish: T = tanh(sum 16 partials + bias)
__global__ __launch_bounds__(256) void k_readout_fin(const float* __restrict__ Tp,
                                                     const float* __restrict__ bo,
                                                     float* __restrict__ T) {
    int i = blockIdx.x * 256 + threadIdx.x;
    int j = i & 511;
    float s = 0.f;
#pragma unroll
    for (int kc = 0; kc < 16; ++kc) s += Tp[(size_t)kc * 32768 + i];
    T[i] = tanhf(s + bo[j]);
}

// ---------------------------------------------------------------------------
// 7. logits, j-tile 64 -> grid 500. Thread tile 4b x 4j, LDS [64][33].
__global__ __launch_bounds__(256) void k_logits(const float* __restrict__ T,
                                                const float* __restrict__ table,
                                                float* __restrict__ out) {
    int j0 = blockIdx.x * 64;
    __shared__ float Ts[64][33];
    __shared__ float Es[64][33];
    int tid = threadIdx.x;
    int tx = tid & 15, ty = tid >> 4;
    float acc[4][4];
#pragma unroll
    for (int i = 0; i < 4; ++i)
#pragma unroll
        for (int j = 0; j < 4; ++j) acc[i][j] = 0.f;
    for (int k0 = 0; k0 < 512; k0 += 32) {
        __syncthreads();
#pragma unroll
        for (int i = 0; i < 8; ++i) {
            int idx = tid + i * 256;
            int kk = idx & 31, bb = idx >> 5;
            Ts[bb][kk] = T[(size_t)bb * 512 + k0 + kk];
        }
#pragma unroll
        for (int i = 0; i < 8; ++i) {
            int idx = tid + i * 256;
            int kk = idx & 31, jj = idx >> 5;
            Es[jj][kk] = table[(size_t)(j0 + jj) * 512 + k0 + kk];
        }
        __syncthreads();
#pragma unroll
        for (int kk = 0; kk < 32; ++kk) {
            float x0 = Ts[ty * 4 + 0][kk];
            float x1 = Ts[ty * 4 + 1][kk];
            float x2 = Ts[ty * 4 + 2][kk];
            float x3 = Ts[ty * 4 + 3][kk];
            float e0 = Es[tx * 4 + 0][kk];
            float e1 = Es[tx * 4 + 1][kk];
            float e2 = Es[tx * 4 + 2][kk];
            float e3 = Es[tx * 4 + 3][kk];
            acc[0][0] += x0 * e0; acc[0][1] += x0 * e1; acc[0][2] += x0 * e2; acc[0][3] += x0 * e3;
            acc[1][0] += x1 * e0; acc[1][1] += x1 * e1; acc[1][2] += x1 * e2; acc[1][3] += x1 * e3;
            acc[2][0] += x2 * e0; acc[2][1] += x2 * e1; acc[2][2] += x2 * e2; acc[2][3] += x2 * e3;
            acc[3][0] += x3 * e0; acc[3][1] += x3 * e1; acc[3][2] += x3 * e2; acc[3][3] += x3 * e3;
        }
    }
#pragma unroll
    for (int ri = 0; ri < 4; ++ri) {
        int bb = ty * 4 + ri;
#pragma unroll
        for (int cj = 0; cj < 4; ++cj)
            out[(size_t)bb * 32000 + j0 + tx * 4 + cj] = acc[ri][cj];
    }
}

// ---------------------------------------------------------------------------
extern "C" void kernel_launch(void* const* d_in, const int* in_sizes, int n_in,
                              void* d_out, int out_size, void* d_ws, size_t ws_size,
                              hipStream_t stream) {
    const int*      tok   = (const int*)d_in[0];
    const float*    h0    = (const float*)d_in[1];
    const float*    c0    = (const float*)d_in[2];
    const float*    enc   = (const float*)d_in[3];
    const unsigned* mask  = (const unsigned*)d_in[4];
    const float*    table = (const float*)d_in[5];
    const float*    We    = (const float*)d_in[6];
    const float*    Wd    = (const float*)d_in[7];
    const float*    va    = (const float*)d_in[8];
    const float*    Wih   = (const float*)d_in[9];
    const float*    Whh   = (const float*)d_in[10];
    const float*    bih   = (const float*)d_in[11];
    const float*    bhh   = (const float*)d_in[12];
    const float*    Wo    = (const float*)d_in[13];
    const float*    bo    = (const float*)d_in[14];

    float* out    = (float*)d_out;
    float* logits = out;                      // 64*32000 = 2048000
    float* out_h  = out + 2048000;            // 65536
    float* out_c  = out + 2048000 + 65536;    // 65536
    float* out_w  = out + 2048000 + 131072;   // 32768

    float* ws     = (float*)d_ws;
    float* emb    = ws;             // 32768
    float* dp     = ws + 32768;     // 16384
    float* scores = ws + 49152;     // 32768
    float* ctx    = ws + 81920;     // 65536
    float* big    = ws + 147456;    // 524288 floats scratch (gates p7 / readout Tp)
    float* T      = ws + 671744;    // 32768
    ushort* Wbf   = (ushort*)(ws + 704512);   // 262144 bf16 (131072 float-slots)

    float* gates_p0 = logits;       // kc 0..6 partials, later overwritten by k_logits
    float* gates_p7 = big;          // kc 7 partial
    float* Tp       = big;          // readout partials (after k_lstm consumed gates)

    k_prep        <<<384, 256, 0, stream>>>(tok, table, We, h0, Wd, emb, Wbf, dp);
    k_scores_mfma <<<512, 256, 0, stream>>>(enc, Wbf, dp, va, scores);
    k_ctx         <<<dim3(8, 64), 256, 0, stream>>>(scores, mask, enc, out_w, ctx);
    k_gates_part  <<<dim3(64, 8), 256, 0, stream>>>(emb, ctx, h0, Wih, Whh, gates_p0, gates_p7);
    k_lstm        <<<256, 256, 0, stream>>>(gates_p0, gates_p7, bih, bhh, c0, out_h, out_c);
    k_readout_part<<<dim3(32, 16), 256, 0, stream>>>(out_h, ctx, emb, Wo, Tp);
    k_readout_fin <<<128, 256, 0, stream>>>(Tp, bo, T);
    k_logits      <<<500, 256, 0, stream>>>(T, table, logits);
}

// Round 6
// 211.631 us; speedup vs baseline: 4.1199x; 1.0134x over previous
//
#include <hip/hip_runtime.h>
#include <hip/hip_bf16.h>
#include <math.h>

// B=64, S=512, VOCAB=32000, EMBED=512, HIDDEN=1024, ENC=1024, ATTN=256

typedef float f32x4 __attribute__((ext_vector_type(4)));
typedef short s16x8 __attribute__((ext_vector_type(8)));

__device__ __forceinline__ float sigmoidf_(float x) { return 1.0f / (1.0f + expf(-x)); }

__device__ __forceinline__ ushort f2bf(float f) {
    __hip_bfloat16 h = __float2bfloat16(f);
    return *reinterpret_cast<ushort*>(&h);
}

// ---------------------------------------------------------------------------
// 1. prep: blocks 0..63 embed gather | 64..319 We->bf16 | 320..383 dec_proj
__global__ __launch_bounds__(256) void k_prep(const int* __restrict__ tok,
                                              const float* __restrict__ table,
                                              const float* __restrict__ We,
                                              const float* __restrict__ h0,
                                              const float* __restrict__ Wd,
                                              float* __restrict__ emb,
                                              ushort* __restrict__ Wbf,
                                              float* __restrict__ dp) {
    __shared__ float sh[1024];
    int bx = blockIdx.x;
    int tid = threadIdx.x;
    if (bx < 64) {
        int b = bx;
        int t = tok[b];
        const float4* src = (const float4*)(table + (size_t)t * 512);
        float4* dst = (float4*)(emb + (size_t)b * 512);
        if (tid < 128) dst[tid] = src[tid];
    } else if (bx < 320) {
        int i = (bx - 64) * 256 + tid;
        float4 f = ((const float4*)We)[i];
        ushort4 o;
        o.x = f2bf(f.x); o.y = f2bf(f.y); o.z = f2bf(f.z); o.w = f2bf(f.w);
        ((ushort4*)Wbf)[i] = o;
    } else {
        int b = bx - 320;
        int a = tid;
        for (int i = tid; i < 1024; i += 256) sh[i] = h0[(size_t)b * 1024 + i];
        __syncthreads();
        const float* w = Wd + (size_t)a * 1024;
        float acc = 0.f;
#pragma unroll 4
        for (int k = 0; k < 1024; k += 4) {
            float4 w4 = *(const float4*)(w + k);
            float4 h4 = *(const float4*)(sh + k);
            acc += w4.x * h4.x + w4.y * h4.y + w4.z * h4.z + w4.w * h4.w;
        }
        dp[b * 256 + a] = acc;
    }
}

// ---------------------------------------------------------------------------
// 2. fused scores (MFMA) + mask + chunk softmax + partial context (flash-style).
//    grid 512 = (b, s-chunk of 64). Writes masked scores, chunk stats (m,sum),
//    and unnormalized partial context ctxp[b][sc][1024].
__global__ __launch_bounds__(256, 3) void k_scores_ctx(const float* __restrict__ enc,
                                                       const ushort* __restrict__ Wbf,
                                                       const float* __restrict__ dp,
                                                       const float* __restrict__ v,
                                                       const unsigned* __restrict__ mask,
                                                       float* __restrict__ scores,
                                                       float* __restrict__ stats,
                                                       float* __restrict__ ctxp) {
    int b  = blockIdx.x >> 3;
    int sc = blockIdx.x & 7;
    int s0 = sc << 6;
    int tid = threadIdx.x;
    int wave = tid >> 6, lane = tid & 63;
    int lan = lane & 15, lk = lane >> 4;

    __shared__ s16x8 Al[512];    // 64 rows x 8 koct
    __shared__ s16x8 Bl[2048];   // 256 a  x 8 koct
    __shared__ float sdp[256], sv[256];
    __shared__ float ss[64];     // chunk scores
    __shared__ float ps[64];     // chunk exp weights
    __shared__ int flag;

    sdp[tid] = dp[b * 256 + tid];
    sv[tid]  = v[tid];

    // mask storage-layout detection (byte-packed vs int32)
    int bad = 0;
    for (int i = tid; i < 512; i += 256)
        if (mask[i] > 1u) bad = 1;
    if (tid == 0) flag = 0;
    __syncthreads();
    if (bad) atomicOr(&flag, 1);

    const float* encB = enc + ((size_t)(b * 512 + s0)) * 1024;

    f32x4 acc[16];
#pragma unroll
    for (int ni = 0; ni < 16; ++ni) acc[ni] = (f32x4){0.f, 0.f, 0.f, 0.f};

    for (int k0 = 0; k0 < 1024; k0 += 64) {
        __syncthreads();
#pragma unroll
        for (int it = 0; it < 2; ++it) {
            int idx = tid + it * 256;
            int row = idx >> 3, koct = idx & 7;
            const float* src = encB + (size_t)row * 1024 + k0 + koct * 8;
            float4 f0 = *(const float4*)src;
            float4 f1 = *(const float4*)(src + 4);
            s16x8 pk;
            pk[0] = (short)f2bf(f0.x); pk[1] = (short)f2bf(f0.y);
            pk[2] = (short)f2bf(f0.z); pk[3] = (short)f2bf(f0.w);
            pk[4] = (short)f2bf(f1.x); pk[5] = (short)f2bf(f1.y);
            pk[6] = (short)f2bf(f1.z); pk[7] = (short)f2bf(f1.w);
            Al[row * 8 + (koct ^ (row & 7))] = pk;
        }
#pragma unroll
        for (int it = 0; it < 8; ++it) {
            int idx = tid + it * 256;
            int a = idx >> 3, koct = idx & 7;
            s16x8 wv = *(const s16x8*)(Wbf + (size_t)a * 1024 + k0 + koct * 8);
            Bl[a * 8 + (koct ^ (a & 7))] = wv;
        }
        __syncthreads();
#pragma unroll
        for (int ks = 0; ks < 2; ++ks) {
            int arow = wave * 16 + lan;
            int akoct = ks * 4 + lk;
            s16x8 af = Al[arow * 8 + (akoct ^ (arow & 7))];
#pragma unroll
            for (int ni = 0; ni < 16; ++ni) {
                int a = ni * 16 + lan;
                s16x8 bf = Bl[a * 8 + (akoct ^ (a & 7))];
                acc[ni] = __builtin_amdgcn_mfma_f32_16x16x32_bf16(af, bf, acc[ni], 0, 0, 0);
            }
        }
    }

    // epilogue: s_row score = sum_a tanh(acc + dp[a]) * v[a]
    float rsum[4] = {0.f, 0.f, 0.f, 0.f};
#pragma unroll
    for (int ni = 0; ni < 16; ++ni) {
        int a = ni * 16 + lan;
        float dpv = sdp[a], vv = sv[a];
#pragma unroll
        for (int r = 0; r < 4; ++r) {
            float x = acc[ni][r] + dpv;
            float t = 1.f - 2.f / (1.f + __expf(2.f * x));   // tanh
            rsum[r] += t * vv;
        }
    }
#pragma unroll
    for (int off = 1; off < 16; off <<= 1) {
#pragma unroll
        for (int r = 0; r < 4; ++r) rsum[r] += __shfl_xor(rsum[r], off);
    }
    if (lan == 0) {
#pragma unroll
        for (int r = 0; r < 4; ++r) ss[wave * 16 + lk * 4 + r] = rsum[r];
    }
    __syncthreads();

    // wave 0: mask, write scores, chunk max/sum, exp weights
    bool u8 = (flag != 0);
    if (tid < 64) {
        int s = s0 + tid;
        bool m = u8 ? (((const unsigned char*)mask)[(size_t)b * 512 + s] != 0)
                    : (mask[(size_t)b * 512 + s] != 0u);
        float val = m ? ss[tid] : -1e9f;
        scores[(size_t)b * 512 + s] = val;
        float mx = val;
#pragma unroll
        for (int off = 1; off < 64; off <<= 1) mx = fmaxf(mx, __shfl_xor(mx, off));
        float e = __expf(val - mx);
        float sum = e;
#pragma unroll
        for (int off = 1; off < 64; off <<= 1) sum += __shfl_xor(sum, off);
        ps[tid] = e;
        if (tid == 0) {
            stats[((size_t)b * 8 + sc) * 2]     = mx;
            stats[((size_t)b * 8 + sc) * 2 + 1] = sum;
        }
    }
    __syncthreads();

    // PV: partial context over this chunk's 64 rows (enc tile is L2/L3-warm)
    f32x4 cacc = (f32x4){0.f, 0.f, 0.f, 0.f};
    const float* eb = encB + tid * 4;
#pragma unroll 8
    for (int s = 0; s < 64; ++s) {
        f32x4 ev = *(const f32x4*)(eb + (size_t)s * 1024);
        float pv = ps[s];
        cacc += pv * ev;
    }
    *(f32x4*)(ctxp + ((size_t)(b * 8 + sc)) * 1024 + tid * 4) = cacc;
}

// ---------------------------------------------------------------------------
// 3. combine chunk partials -> ctx, out_w. grid 64 (one block per b).
__global__ __launch_bounds__(256) void k_ctx_fin(const float* __restrict__ stats,
                                                 const float* __restrict__ scores,
                                                 const float* __restrict__ ctxp,
                                                 float* __restrict__ out_w,
                                                 float* __restrict__ ctx) {
    int b = blockIdx.x;
    int tid = threadIdx.x;
    __shared__ float sm[8], ssum[8];
    if (tid < 8) {
        sm[tid]   = stats[((size_t)b * 8 + tid) * 2];
        ssum[tid] = stats[((size_t)b * 8 + tid) * 2 + 1];
    }
    __syncthreads();
    float M = sm[0];
#pragma unroll
    for (int i = 1; i < 8; ++i) M = fmaxf(M, sm[i]);
    float total = 0.f;
#pragma unroll
    for (int i = 0; i < 8; ++i) total += ssum[i] * __expf(sm[i] - M);
    float inv = 1.f / total;

    // weights
    out_w[(size_t)b * 512 + tid]       = __expf(scores[(size_t)b * 512 + tid] - M) * inv;
    out_w[(size_t)b * 512 + tid + 256] = __expf(scores[(size_t)b * 512 + tid + 256] - M) * inv;

    // context
    f32x4 acc = (f32x4){0.f, 0.f, 0.f, 0.f};
#pragma unroll
    for (int sc = 0; sc < 8; ++sc) {
        float w = __expf(sm[sc] - M) * inv;
        f32x4 p = *(const f32x4*)(ctxp + ((size_t)(b * 8 + sc)) * 1024 + tid * 4);
        acc += w * p;
    }
    *(f32x4*)(ctx + (size_t)b * 1024 + tid * 4) = acc;
}

// ---------------------------------------------------------------------------
// 4. gates partial GEMM. grid (64 j-tiles of 64, 8 K-chunks of 320).
__global__ __launch_bounds__(256) void k_gates_part(const float* __restrict__ emb,
                                                    const float* __restrict__ ctx,
                                                    const float* __restrict__ h,
                                                    const float* __restrict__ Wih,
                                                    const float* __restrict__ Whh,
                                                    float* __restrict__ p0,
                                                    float* __restrict__ p7) {
    int j0 = blockIdx.x * 64;
    int kc = blockIdx.y;
    __shared__ float Xs[64][33];
    __shared__ float Ws[64][33];
    int tid = threadIdx.x;
    int tx = tid & 15, ty = tid >> 4;
    float acc[4][4];
#pragma unroll
    for (int i = 0; i < 4; ++i)
#pragma unroll
        for (int j = 0; j < 4; ++j) acc[i][j] = 0.f;

    for (int k0 = kc * 320; k0 < kc * 320 + 320; k0 += 32) {
        const float* xsrc; int xstride, xoff;
        if (k0 < 512)       { xsrc = emb; xstride = 512;  xoff = k0; }
        else if (k0 < 1536) { xsrc = ctx; xstride = 1024; xoff = k0 - 512; }
        else                { xsrc = h;   xstride = 1024; xoff = k0 - 1536; }
        const float* wsrc; int wstride, woff;
        if (k0 < 1536) { wsrc = Wih; wstride = 1536; woff = k0; }
        else           { wsrc = Whh; wstride = 1024; woff = k0 - 1536; }
        __syncthreads();
#pragma unroll
        for (int i = 0; i < 8; ++i) {
            int idx = tid + i * 256;
            int kk = idx & 31, bb = idx >> 5;
            Xs[bb][kk] = xsrc[(size_t)bb * xstride + xoff + kk];
        }
#pragma unroll
        for (int i = 0; i < 8; ++i) {
            int idx = tid + i * 256;
            int kk = idx & 31, jj = idx >> 5;
            Ws[jj][kk] = wsrc[(size_t)(j0 + jj) * wstride + woff + kk];
        }
        __syncthreads();
#pragma unroll
        for (int kk = 0; kk < 32; ++kk) {
            float x0 = Xs[ty * 4 + 0][kk];
            float x1 = Xs[ty * 4 + 1][kk];
            float x2 = Xs[ty * 4 + 2][kk];
            float x3 = Xs[ty * 4 + 3][kk];
            float w0 = Ws[tx * 4 + 0][kk];
            float w1 = Ws[tx * 4 + 1][kk];
            float w2 = Ws[tx * 4 + 2][kk];
            float w3 = Ws[tx * 4 + 3][kk];
            acc[0][0] += x0 * w0; acc[0][1] += x0 * w1; acc[0][2] += x0 * w2; acc[0][3] += x0 * w3;
            acc[1][0] += x1 * w0; acc[1][1] += x1 * w1; acc[1][2] += x1 * w2; acc[1][3] += x1 * w3;
            acc[2][0] += x2 * w0; acc[2][1] += x2 * w1; acc[2][2] += x2 * w2; acc[2][3] += x2 * w3;
            acc[3][0] += x3 * w0; acc[3][1] += x3 * w1; acc[3][2] += x3 * w2; acc[3][3] += x3 * w3;
        }
    }
    float* dst = (kc < 7) ? (p0 + (size_t)kc * 262144) : p7;
#pragma unroll
    for (int ri = 0; ri < 4; ++ri) {
        int bb = ty * 4 + ri;
#pragma unroll
        for (int cj = 0; cj < 4; ++cj)
            dst[(size_t)bb * 4096 + j0 + tx * 4 + cj] = acc[ri][cj];
    }
}

// ---------------------------------------------------------------------------
// 5. LSTM elementwise + 8-way partial reduce
__global__ __launch_bounds__(256) void k_lstm(const float* __restrict__ p0,
                                              const float* __restrict__ p7,
                                              const float* __restrict__ bih,
                                              const float* __restrict__ bhh,
                                              const float* __restrict__ c0,
                                              float* __restrict__ out_h,
                                              float* __restrict__ out_c) {
    int idx = blockIdx.x * 256 + threadIdx.x;
    int b = idx >> 10, hh = idx & 1023;
    float g[4];
#pragma unroll
    for (int gt = 0; gt < 4; ++gt) {
        size_t off = (size_t)b * 4096 + gt * 1024 + hh;
        float s = p7[off] + bih[gt * 1024 + hh] + bhh[gt * 1024 + hh];
#pragma unroll
        for (int kc = 0; kc < 7; ++kc) s += p0[(size_t)kc * 262144 + off];
        g[gt] = s;
    }
    float c_old = c0[idx];
    float nc = sigmoidf_(g[1]) * c_old + sigmoidf_(g[0]) * tanhf(g[2]);
    float nh = sigmoidf_(g[3]) * tanhf(nc);
    out_h[idx] = nh;
    out_c[idx] = nc;
}

// ---------------------------------------------------------------------------
// 6a. readout partials: grid (32 j-tiles of 16, 16 K-chunks of 160).
__global__ __launch_bounds__(256) void k_readout_part(const float* __restrict__ nh,
                                                      const float* __restrict__ ctx,
                                                      const float* __restrict__ emb,
                                                      const float* __restrict__ Wo,
                                                      float* __restrict__ Tp) {
    int j0 = blockIdx.x * 16;
    int kc = blockIdx.y;
    __shared__ float Xs[64][33];
    __shared__ float Ws[16][33];
    int tid = threadIdx.x;
    int b = tid & 63, jg = tid >> 6;
    float acc[4] = {0.f, 0.f, 0.f, 0.f};

    for (int k0 = kc * 160; k0 < kc * 160 + 160; k0 += 32) {
        const float* xsrc; int xstride, xoff;
        if (k0 < 1024)      { xsrc = nh;  xstride = 1024; xoff = k0; }
        else if (k0 < 2048) { xsrc = ctx; xstride = 1024; xoff = k0 - 1024; }
        else                { xsrc = emb; xstride = 512;  xoff = k0 - 2048; }
        __syncthreads();
#pragma unroll
        for (int i = 0; i < 8; ++i) {
            int idx = tid + i * 256;
            int kk = idx & 31, bb = idx >> 5;
            Xs[bb][kk] = xsrc[(size_t)bb * xstride + xoff + kk];
        }
#pragma unroll
        for (int i = 0; i < 2; ++i) {
            int idx = tid + i * 256;
            int kk = idx & 31, jj = idx >> 5;
            Ws[jj][kk] = Wo[(size_t)(j0 + jj) * 2560 + k0 + kk];
        }
        __syncthreads();
#pragma unroll
        for (int kk = 0; kk < 32; ++kk) {
            float x = Xs[b][kk];
            acc[0] += x * Ws[jg * 4 + 0][kk];
            acc[1] += x * Ws[jg * 4 + 1][kk];
            acc[2] += x * Ws[jg * 4 + 2][kk];
            acc[3] += x * Ws[jg * 4 + 3][kk];
        }
    }
#pragma unroll
    for (int c = 0; c < 4; ++c)
        Tp[((size_t)kc * 64 + b) * 512 + j0 + jg * 4 + c] = acc[c];
}

// 6b. readout finish: T = tanh(sum 16 partials + bias)
__global__ __launch_bounds__(256) void k_readout_fin(const float* __restrict__ Tp,
                                                     const float* __restrict__ bo,
                                                     float* __restrict__ T) {
    int i = blockIdx.x * 256 + threadIdx.x;
    int j = i & 511;
    float s = 0.f;
#pragma unroll
    for (int kc = 0; kc < 16; ++kc) s += Tp[(size_t)kc * 32768 + i];
    T[i] = tanhf(s + bo[j]);
}

// ---------------------------------------------------------------------------
// 7. logits, j-tile 64 -> grid 500. Thread tile 4b x 4j, LDS [64][33].
__global__ __launch_bounds__(256) void k_logits(const float* __restrict__ T,
                                                const float* __restrict__ table,
                                                float* __restrict__ out) {
    int j0 = blockIdx.x * 64;
    __shared__ float Ts[64][33];
    __shared__ float Es[64][33];
    int tid = threadIdx.x;
    int tx = tid & 15, ty = tid >> 4;
    float acc[4][4];
#pragma unroll
    for (int i = 0; i < 4; ++i)
#pragma unroll
        for (int j = 0; j < 4; ++j) acc[i][j] = 0.f;
    for (int k0 = 0; k0 < 512; k0 += 32) {
        __syncthreads();
#pragma unroll
        for (int i = 0; i < 8; ++i) {
            int idx = tid + i * 256;
            int kk = idx & 31, bb = idx >> 5;
            Ts[bb][kk] = T[(size_t)bb * 512 + k0 + kk];
        }
#pragma unroll
        for (int i = 0; i < 8; ++i) {
            int idx = tid + i * 256;
            int kk = idx & 31, jj = idx >> 5;
            Es[jj][kk] = table[(size_t)(j0 + jj) * 512 + k0 + kk];
        }
        __syncthreads();
#pragma unroll
        for (int kk = 0; kk < 32; ++kk) {
            float x0 = Ts[ty * 4 + 0][kk];
            float x1 = Ts[ty * 4 + 1][kk];
            float x2 = Ts[ty * 4 + 2][kk];
            float x3 = Ts[ty * 4 + 3][kk];
            float e0 = Es[tx * 4 + 0][kk];
            float e1 = Es[tx * 4 + 1][kk];
            float e2 = Es[tx * 4 + 2][kk];
            float e3 = Es[tx * 4 + 3][kk];
            acc[0][0] += x0 * e0; acc[0][1] += x0 * e1; acc[0][2] += x0 * e2; acc[0][3] += x0 * e3;
            acc[1][0] += x1 * e0; acc[1][1] += x1 * e1; acc[1][2] += x1 * e2; acc[1][3] += x1 * e3;
            acc[2][0] += x2 * e0; acc[2][1] += x2 * e1; acc[2][2] += x2 * e2; acc[2][3] += x2 * e3;
            acc[3][0] += x3 * e0; acc[3][1] += x3 * e1; acc[3][2] += x3 * e2; acc[3][3] += x3 * e3;
        }
    }
#pragma unroll
    for (int ri = 0; ri < 4; ++ri) {
        int bb = ty * 4 + ri;
#pragma unroll
        for (int cj = 0; cj < 4; ++cj)
            out[(size_t)bb * 32000 + j0 + tx * 4 + cj] = acc[ri][cj];
    }
}

// ---------------------------------------------------------------------------
extern "C" void kernel_launch(void* const* d_in, const int* in_sizes, int n_in,
                              void* d_out, int out_size, void* d_ws, size_t ws_size,
                              hipStream_t stream) {
    const int*      tok   = (const int*)d_in[0];
    const float*    h0    = (const float*)d_in[1];
    const float*    c0    = (const float*)d_in[2];
    const float*    enc   = (const float*)d_in[3];
    const unsigned* mask  = (const unsigned*)d_in[4];
    const float*    table = (const float*)d_in[5];
    const float*    We    = (const float*)d_in[6];
    const float*    Wd    = (const float*)d_in[7];
    const float*    va    = (const float*)d_in[8];
    const float*    Wih   = (const float*)d_in[9];
    const float*    Whh   = (const float*)d_in[10];
    const float*    bih   = (const float*)d_in[11];
    const float*    bhh   = (const float*)d_in[12];
    const float*    Wo    = (const float*)d_in[13];
    const float*    bo    = (const float*)d_in[14];

    float* out    = (float*)d_out;
    float* logits = out;                      // 64*32000 = 2048000
    float* out_h  = out + 2048000;            // 65536
    float* out_c  = out + 2048000 + 65536;    // 65536
    float* out_w  = out + 2048000 + 131072;   // 32768

    float* ws     = (float*)d_ws;
    float* emb    = ws;             // 32768
    float* dp     = ws + 32768;     // 16384
    float* scores = ws + 49152;     // 32768
    float* ctx    = ws + 81920;     // 65536
    float* big    = ws + 147456;    // 524288 floats (ctxp / gates p7 / readout Tp)
    float* T      = ws + 671744;    // 32768
    ushort* Wbf   = (ushort*)(ws + 704512);   // 262144 bf16 (131072 float-slots)
    float* stats  = ws + 835584;    // 1024

    float* ctxp     = big;          // 64*8*1024 partial contexts
    float* gates_p0 = logits;       // kc 0..6 partials, later overwritten by k_logits
    float* gates_p7 = big;          // kc 7 partial (after ctxp consumed)
    float* Tp       = big;          // readout partials (after k_lstm consumed gates)

    k_prep        <<<384, 256, 0, stream>>>(tok, table, We, h0, Wd, emb, Wbf, dp);
    k_scores_ctx  <<<512, 256, 0, stream>>>(enc, Wbf, dp, va, mask, scores, stats, ctxp);
    k_ctx_fin     <<<64, 256, 0, stream>>>(stats, scores, ctxp, out_w, ctx);
    k_gates_part  <<<dim3(64, 8), 256, 0, stream>>>(emb, ctx, h0, Wih, Whh, gates_p0, gates_p7);
    k_lstm        <<<256, 256, 0, stream>>>(gates_p0, gates_p7, bih, bhh, c0, out_h, out_c);
    k_readout_part<<<dim3(32, 16), 256, 0, stream>>>(out_h, ctx, emb, Wo, Tp);
    k_readout_fin <<<128, 256, 0, stream>>>(Tp, bo, T);
    k_logits      <<<500, 256, 0, stream>>>(T, table, logits);
}

// Round 7
// 211.119 us; speedup vs baseline: 4.1299x; 1.0024x over previous
//
#include <hip/hip_runtime.h>
#include <hip/hip_bf16.h>
#include <math.h>

// B=64, S=512, VOCAB=32000, EMBED=512, HIDDEN=1024, ENC=1024, ATTN=256

typedef float f32x4 __attribute__((ext_vector_type(4)));
typedef short s16x8 __attribute__((ext_vector_type(8)));

__device__ __forceinline__ float sigmoidf_(float x) { return 1.0f / (1.0f + expf(-x)); }

__device__ __forceinline__ ushort f2bf(float f) {
    __hip_bfloat16 h = __float2bfloat16(f);
    return *reinterpret_cast<ushort*>(&h);
}

// ---------------------------------------------------------------------------
// 1. prep: blocks 0..63 embed gather | 64..319 We->bf16 | 320..383 dec_proj
__global__ __launch_bounds__(256) void k_prep(const int* __restrict__ tok,
                                              const float* __restrict__ table,
                                              const float* __restrict__ We,
                                              const float* __restrict__ h0,
                                              const float* __restrict__ Wd,
                                              float* __restrict__ emb,
                                              ushort* __restrict__ Wbf,
                                              float* __restrict__ dp) {
    __shared__ float sh[1024];
    int bx = blockIdx.x;
    int tid = threadIdx.x;
    if (bx < 64) {
        int b = bx;
        int t = tok[b];
        const float4* src = (const float4*)(table + (size_t)t * 512);
        float4* dst = (float4*)(emb + (size_t)b * 512);
        if (tid < 128) dst[tid] = src[tid];
    } else if (bx < 320) {
        int i = (bx - 64) * 256 + tid;
        float4 f = ((const float4*)We)[i];
        ushort4 o;
        o.x = f2bf(f.x); o.y = f2bf(f.y); o.z = f2bf(f.z); o.w = f2bf(f.w);
        ((ushort4*)Wbf)[i] = o;
    } else {
        int b = bx - 320;
        int a = tid;
        for (int i = tid; i < 1024; i += 256) sh[i] = h0[(size_t)b * 1024 + i];
        __syncthreads();
        const float* w = Wd + (size_t)a * 1024;
        float acc = 0.f;
#pragma unroll 4
        for (int k = 0; k < 1024; k += 4) {
            float4 w4 = *(const float4*)(w + k);
            float4 h4 = *(const float4*)(sh + k);
            acc += w4.x * h4.x + w4.y * h4.y + w4.z * h4.z + w4.w * h4.w;
        }
        dp[b * 256 + a] = acc;
    }
}

// ---------------------------------------------------------------------------
// 2. fused scores (MFMA) + mask + chunk softmax + partial context.
//    Pipelined: B staged via global_load_lds (double-buffered, pre-swizzled
//    source so the XOR bank-swizzle survives the linear LDS dest); A loaded
//    direct global->reg, prefetched one K-tile ahead. One barrier per K-step.
__global__ __launch_bounds__(256, 2) void k_scores_ctx(const float* __restrict__ enc,
                                                       const ushort* __restrict__ Wbf,
                                                       const float* __restrict__ dp,
                                                       const float* __restrict__ v,
                                                       const unsigned* __restrict__ mask,
                                                       float* __restrict__ scores,
                                                       float* __restrict__ stats,
                                                       float* __restrict__ ctxp) {
    int b  = blockIdx.x >> 3;
    int sc = blockIdx.x & 7;
    int s0 = sc << 6;
    int tid = threadIdx.x;
    int wave = tid >> 6, lane = tid & 63;
    int lan = lane & 15, lk = lane >> 4;

    __shared__ s16x8 Bl[2][2048];   // 2 x 32 KB: slot = a*8 + (koct ^ (a&7))
    __shared__ float sdp[256], sv[256];
    __shared__ float ss[64];
    __shared__ float ps[64];
    __shared__ int flag;

    sdp[tid] = dp[b * 256 + tid];
    sv[tid]  = v[tid];
    int bad = 0;
    for (int i = tid; i < 512; i += 256)
        if (mask[i] > 1u) bad = 1;
    if (tid == 0) flag = 0;

    const float* encRow = enc + ((size_t)(b * 512 + s0 + wave * 16 + lan)) * 1024;

    // stage one 64-K tile of B into Bl[bufIdx] via global_load_lds.
    // dest slot d = it*256 + wave*64 + lane (linear); source pre-swizzled:
    // slot d holds Wbf[a][koct] with a=d>>3, koct=(d&7)^(a&7).
    auto stageB = [&](int bufIdx, int k0) {
#pragma unroll
        for (int it = 0; it < 8; ++it) {
            int dbase = it * 256 + wave * 64;
            int d = dbase + lane;
            int a = d >> 3, j = d & 7;
            const ushort* src = Wbf + (size_t)a * 1024 + k0 + ((j ^ (a & 7)) << 3);
            __builtin_amdgcn_global_load_lds(
                (const __attribute__((address_space(1))) void*)src,
                (__attribute__((address_space(3))) void*)&Bl[bufIdx][dbase],
                16, 0, 0);
        }
    };

    f32x4 acc[16];
#pragma unroll
    for (int ni = 0; ni < 16; ++ni) acc[ni] = (f32x4){0.f, 0.f, 0.f, 0.f};

    // prologue: A(t=0) into regs, B(t=0) into buf 0
    float4 a0, a1, a2, a3;
    {
        const float* p0 = encRow + lk * 8;
        const float* p1 = encRow + (lk + 4) * 8;
        a0 = *(const float4*)p0; a1 = *(const float4*)(p0 + 4);
        a2 = *(const float4*)p1; a3 = *(const float4*)(p1 + 4);
    }
    stageB(0, 0);
    __syncthreads();                    // drains vmcnt; flag=0 visible
    if (bad) atomicOr(&flag, 1);

    for (int t = 0; t < 16; ++t) {
        int cur = t & 1, nxt = cur ^ 1;
        float4 b0 = {0,0,0,0}, b1 = {0,0,0,0}, b2 = {0,0,0,0}, b3 = {0,0,0,0};
        if (t < 15) {
            int k1 = (t + 1) * 64;
            stageB(nxt, k1);            // in-flight across the MFMA block
            const float* p0 = encRow + k1 + lk * 8;
            const float* p1 = encRow + k1 + (lk + 4) * 8;
            b0 = *(const float4*)p0; b1 = *(const float4*)(p0 + 4);
            b2 = *(const float4*)p1; b3 = *(const float4*)(p1 + 4);
        }
        s16x8 af0, af1;
        af0[0] = (short)f2bf(a0.x); af0[1] = (short)f2bf(a0.y);
        af0[2] = (short)f2bf(a0.z); af0[3] = (short)f2bf(a0.w);
        af0[4] = (short)f2bf(a1.x); af0[5] = (short)f2bf(a1.y);
        af0[6] = (short)f2bf(a1.z); af0[7] = (short)f2bf(a1.w);
        af1[0] = (short)f2bf(a2.x); af1[1] = (short)f2bf(a2.y);
        af1[2] = (short)f2bf(a2.z); af1[3] = (short)f2bf(a2.w);
        af1[4] = (short)f2bf(a3.x); af1[5] = (short)f2bf(a3.y);
        af1[6] = (short)f2bf(a3.z); af1[7] = (short)f2bf(a3.w);
#pragma unroll
        for (int ni = 0; ni < 16; ++ni) {
            int a = ni * 16 + lan;
            s16x8 bf = Bl[cur][a * 8 + (lk ^ (a & 7))];
            acc[ni] = __builtin_amdgcn_mfma_f32_16x16x32_bf16(af0, bf, acc[ni], 0, 0, 0);
        }
#pragma unroll
        for (int ni = 0; ni < 16; ++ni) {
            int a = ni * 16 + lan;
            s16x8 bf = Bl[cur][a * 8 + ((lk + 4) ^ (a & 7))];
            acc[ni] = __builtin_amdgcn_mfma_f32_16x16x32_bf16(af1, bf, acc[ni], 0, 0, 0);
        }
        a0 = b0; a1 = b1; a2 = b2; a3 = b3;
        __syncthreads();                // vmcnt(0)+lgkmcnt(0)+barrier: next buf ready
    }

    // epilogue: score[row] = sum_a tanh(acc + dp[a]) * v[a]
    float rsum[4] = {0.f, 0.f, 0.f, 0.f};
#pragma unroll
    for (int ni = 0; ni < 16; ++ni) {
        int a = ni * 16 + lan;
        float dpv = sdp[a], vv = sv[a];
#pragma unroll
        for (int r = 0; r < 4; ++r) {
            float x = acc[ni][r] + dpv;
            float t = 1.f - 2.f / (1.f + __expf(2.f * x));   // tanh
            rsum[r] += t * vv;
        }
    }
#pragma unroll
    for (int off = 1; off < 16; off <<= 1) {
#pragma unroll
        for (int r = 0; r < 4; ++r) rsum[r] += __shfl_xor(rsum[r], off);
    }
    if (lan == 0) {
#pragma unroll
        for (int r = 0; r < 4; ++r) ss[wave * 16 + lk * 4 + r] = rsum[r];
    }
    __syncthreads();

    // wave 0: mask, write scores, chunk max/sum, exp weights
    bool u8 = (flag != 0);
    if (tid < 64) {
        int s = s0 + tid;
        bool m = u8 ? (((const unsigned char*)mask)[(size_t)b * 512 + s] != 0)
                    : (mask[(size_t)b * 512 + s] != 0u);
        float val = m ? ss[tid] : -1e9f;
        scores[(size_t)b * 512 + s] = val;
        float mx = val;
#pragma unroll
        for (int off = 1; off < 64; off <<= 1) mx = fmaxf(mx, __shfl_xor(mx, off));
        float e = __expf(val - mx);
        float sum = e;
#pragma unroll
        for (int off = 1; off < 64; off <<= 1) sum += __shfl_xor(sum, off);
        ps[tid] = e;
        if (tid == 0) {
            stats[((size_t)b * 8 + sc) * 2]     = mx;
            stats[((size_t)b * 8 + sc) * 2 + 1] = sum;
        }
    }
    __syncthreads();

    // PV: partial context over this chunk's 64 rows (enc tile is L2/L3-warm)
    f32x4 cacc = (f32x4){0.f, 0.f, 0.f, 0.f};
    const float* eb = enc + ((size_t)(b * 512 + s0)) * 1024 + tid * 4;
#pragma unroll 8
    for (int s = 0; s < 64; ++s) {
        f32x4 ev = *(const f32x4*)(eb + (size_t)s * 1024);
        float pv = ps[s];
        cacc += pv * ev;
    }
    *(f32x4*)(ctxp + ((size_t)(b * 8 + sc)) * 1024 + tid * 4) = cacc;
}

// ---------------------------------------------------------------------------
// 3. combine chunk partials -> ctx, out_w. grid 64 (one block per b).
__global__ __launch_bounds__(256) void k_ctx_fin(const float* __restrict__ stats,
                                                 const float* __restrict__ scores,
                                                 const float* __restrict__ ctxp,
                                                 float* __restrict__ out_w,
                                                 float* __restrict__ ctx) {
    int b = blockIdx.x;
    int tid = threadIdx.x;
    __shared__ float sm[8], ssum[8];
    if (tid < 8) {
        sm[tid]   = stats[((size_t)b * 8 + tid) * 2];
        ssum[tid] = stats[((size_t)b * 8 + tid) * 2 + 1];
    }
    __syncthreads();
    float M = sm[0];
#pragma unroll
    for (int i = 1; i < 8; ++i) M = fmaxf(M, sm[i]);
    float total = 0.f;
#pragma unroll
    for (int i = 0; i < 8; ++i) total += ssum[i] * __expf(sm[i] - M);
    float inv = 1.f / total;

    out_w[(size_t)b * 512 + tid]       = __expf(scores[(size_t)b * 512 + tid] - M) * inv;
    out_w[(size_t)b * 512 + tid + 256] = __expf(scores[(size_t)b * 512 + tid + 256] - M) * inv;

    f32x4 acc = (f32x4){0.f, 0.f, 0.f, 0.f};
#pragma unroll
    for (int sc = 0; sc < 8; ++sc) {
        float w = __expf(sm[sc] - M) * inv;
        f32x4 p = *(const f32x4*)(ctxp + ((size_t)(b * 8 + sc)) * 1024 + tid * 4);
        acc += w * p;
    }
    *(f32x4*)(ctx + (size_t)b * 1024 + tid * 4) = acc;
}

// ---------------------------------------------------------------------------
// 4. gates partial GEMM. grid (64 j-tiles of 64, 8 K-chunks of 320).
__global__ __launch_bounds__(256) void k_gates_part(const float* __restrict__ emb,
                                                    const float* __restrict__ ctx,
                                                    const float* __restrict__ h,
                                                    const float* __restrict__ Wih,
                                                    const float* __restrict__ Whh,
                                                    float* __restrict__ p0,
                                                    float* __restrict__ p7) {
    int j0 = blockIdx.x * 64;
    int kc = blockIdx.y;
    __shared__ float Xs[64][33];
    __shared__ float Ws[64][33];
    int tid = threadIdx.x;
    int tx = tid & 15, ty = tid >> 4;
    float acc[4][4];
#pragma unroll
    for (int i = 0; i < 4; ++i)
#pragma unroll
        for (int j = 0; j < 4; ++j) acc[i][j] = 0.f;

    for (int k0 = kc * 320; k0 < kc * 320 + 320; k0 += 32) {
        const float* xsrc; int xstride, xoff;
        if (k0 < 512)       { xsrc = emb; xstride = 512;  xoff = k0; }
        else if (k0 < 1536) { xsrc = ctx; xstride = 1024; xoff = k0 - 512; }
        else                { xsrc = h;   xstride = 1024; xoff = k0 - 1536; }
        const float* wsrc; int wstride, woff;
        if (k0 < 1536) { wsrc = Wih; wstride = 1536; woff = k0; }
        else           { wsrc = Whh; wstride = 1024; woff = k0 - 1536; }
        __syncthreads();
#pragma unroll
        for (int i = 0; i < 8; ++i) {
            int idx = tid + i * 256;
            int kk = idx & 31, bb = idx >> 5;
            Xs[bb][kk] = xsrc[(size_t)bb * xstride + xoff + kk];
        }
#pragma unroll
        for (int i = 0; i < 8; ++i) {
            int idx = tid + i * 256;
            int kk = idx & 31, jj = idx >> 5;
            Ws[jj][kk] = wsrc[(size_t)(j0 + jj) * wstride + woff + kk];
        }
        __syncthreads();
#pragma unroll
        for (int kk = 0; kk < 32; ++kk) {
            float x0 = Xs[ty * 4 + 0][kk];
            float x1 = Xs[ty * 4 + 1][kk];
            float x2 = Xs[ty * 4 + 2][kk];
            float x3 = Xs[ty * 4 + 3][kk];
            float w0 = Ws[tx * 4 + 0][kk];
            float w1 = Ws[tx * 4 + 1][kk];
            float w2 = Ws[tx * 4 + 2][kk];
            float w3 = Ws[tx * 4 + 3][kk];
            acc[0][0] += x0 * w0; acc[0][1] += x0 * w1; acc[0][2] += x0 * w2; acc[0][3] += x0 * w3;
            acc[1][0] += x1 * w0; acc[1][1] += x1 * w1; acc[1][2] += x1 * w2; acc[1][3] += x1 * w3;
            acc[2][0] += x2 * w0; acc[2][1] += x2 * w1; acc[2][2] += x2 * w2; acc[2][3] += x2 * w3;
            acc[3][0] += x3 * w0; acc[3][1] += x3 * w1; acc[3][2] += x3 * w2; acc[3][3] += x3 * w3;
        }
    }
    float* dst = (kc < 7) ? (p0 + (size_t)kc * 262144) : p7;
#pragma unroll
    for (int ri = 0; ri < 4; ++ri) {
        int bb = ty * 4 + ri;
#pragma unroll
        for (int cj = 0; cj < 4; ++cj)
            dst[(size_t)bb * 4096 + j0 + tx * 4 + cj] = acc[ri][cj];
    }
}

// ---------------------------------------------------------------------------
// 5. LSTM elementwise + 8-way partial reduce
__global__ __launch_bounds__(256) void k_lstm(const float* __restrict__ p0,
                                              const float* __restrict__ p7,
                                              const float* __restrict__ bih,
                                              const float* __restrict__ bhh,
                                              const float* __restrict__ c0,
                                              float* __restrict__ out_h,
                                              float* __restrict__ out_c) {
    int idx = blockIdx.x * 256 + threadIdx.x;
    int b = idx >> 10, hh = idx & 1023;
    float g[4];
#pragma unroll
    for (int gt = 0; gt < 4; ++gt) {
        size_t off = (size_t)b * 4096 + gt * 1024 + hh;
        float s = p7[off] + bih[gt * 1024 + hh] + bhh[gt * 1024 + hh];
#pragma unroll
        for (int kc = 0; kc < 7; ++kc) s += p0[(size_t)kc * 262144 + off];
        g[gt] = s;
    }
    float c_old = c0[idx];
    float nc = sigmoidf_(g[1]) * c_old + sigmoidf_(g[0]) * tanhf(g[2]);
    float nh = sigmoidf_(g[3]) * tanhf(nc);
    out_h[idx] = nh;
    out_c[idx] = nc;
}

// ---------------------------------------------------------------------------
// 6a. readout partials: grid (32 j-tiles of 16, 16 K-chunks of 160).
__global__ __launch_bounds__(256) void k_readout_part(const float* __restrict__ nh,
                                                      const float* __restrict__ ctx,
                                                      const float* __restrict__ emb,
                                                      const float* __restrict__ Wo,
                                                      float* __restrict__ Tp) {
    int j0 = blockIdx.x * 16;
    int kc = blockIdx.y;
    __shared__ float Xs[64][33];
    __shared__ float Ws[16][33];
    int tid = threadIdx.x;
    int b = tid & 63, jg = tid >> 6;
    float acc[4] = {0.f, 0.f, 0.f, 0.f};

    for (int k0 = kc * 160; k0 < kc * 160 + 160; k0 += 32) {
        const float* xsrc; int xstride, xoff;
        if (k0 < 1024)      { xsrc = nh;  xstride = 1024; xoff = k0; }
        else if (k0 < 2048) { xsrc = ctx; xstride = 1024; xoff = k0 - 1024; }
        else                { xsrc = emb; xstride = 512;  xoff = k0 - 2048; }
        __syncthreads();
#pragma unroll
        for (int i = 0; i < 8; ++i) {
            int idx = tid + i * 256;
            int kk = idx & 31, bb = idx >> 5;
            Xs[bb][kk] = xsrc[(size_t)bb * xstride + xoff + kk];
        }
#pragma unroll
        for (int i = 0; i < 2; ++i) {
            int idx = tid + i * 256;
            int kk = idx & 31, jj = idx >> 5;
            Ws[jj][kk] = Wo[(size_t)(j0 + jj) * 2560 + k0 + kk];
        }
        __syncthreads();
#pragma unroll
        for (int kk = 0; kk < 32; ++kk) {
            float x = Xs[b][kk];
            acc[0] += x * Ws[jg * 4 + 0][kk];
            acc[1] += x * Ws[jg * 4 + 1][kk];
            acc[2] += x * Ws[jg * 4 + 2][kk];
            acc[3] += x * Ws[jg * 4 + 3][kk];
        }
    }
#pragma unroll
    for (int c = 0; c < 4; ++c)
        Tp[((size_t)kc * 64 + b) * 512 + j0 + jg * 4 + c] = acc[c];
}

// 6b. readout finish: T = tanh(sum 16 partials + bias)
__global__ __launch_bounds__(256) void k_readout_fin(const float* __restrict__ Tp,
                                                     const float* __restrict__ bo,
                                                     float* __restrict__ T) {
    int i = blockIdx.x * 256 + threadIdx.x;
    int j = i & 511;
    float s = 0.f;
#pragma unroll
    for (int kc = 0; kc < 16; ++kc) s += Tp[(size_t)kc * 32768 + i];
    T[i] = tanhf(s + bo[j]);
}

// ---------------------------------------------------------------------------
// 7. logits, j-tile 64 -> grid 500. Thread tile 4b x 4j, LDS [64][33].
__global__ __launch_bounds__(256) void k_logits(const float* __restrict__ T,
                                                const float* __restrict__ table,
                                                float* __restrict__ out) {
    int j0 = blockIdx.x * 64;
    __shared__ float Ts[64][33];
    __shared__ float Es[64][33];
    int tid = threadIdx.x;
    int tx = tid & 15, ty = tid >> 4;
    float acc[4][4];
#pragma unroll
    for (int i = 0; i < 4; ++i)
#pragma unroll
        for (int j = 0; j < 4; ++j) acc[i][j] = 0.f;
    for (int k0 = 0; k0 < 512; k0 += 32) {
        __syncthreads();
#pragma unroll
        for (int i = 0; i < 8; ++i) {
            int idx = tid + i * 256;
            int kk = idx & 31, bb = idx >> 5;
            Ts[bb][kk] = T[(size_t)bb * 512 + k0 + kk];
        }
#pragma unroll
        for (int i = 0; i < 8; ++i) {
            int idx = tid + i * 256;
            int kk = idx & 31, jj = idx >> 5;
            Es[jj][kk] = table[(size_t)(j0 + jj) * 512 + k0 + kk];
        }
        __syncthreads();
#pragma unroll
        for (int kk = 0; kk < 32; ++kk) {
            float x0 = Ts[ty * 4 + 0][kk];
            float x1 = Ts[ty * 4 + 1][kk];
            float x2 = Ts[ty * 4 + 2][kk];
            float x3 = Ts[ty * 4 + 3][kk];
            float e0 = Es[tx * 4 + 0][kk];
            float e1 = Es[tx * 4 + 1][kk];
            float e2 = Es[tx * 4 + 2][kk];
            float e3 = Es[tx * 4 + 3][kk];
            acc[0][0] += x0 * e0; acc[0][1] += x0 * e1; acc[0][2] += x0 * e2; acc[0][3] += x0 * e3;
            acc[1][0] += x1 * e0; acc[1][1] += x1 * e1; acc[1][2] += x1 * e2; acc[1][3] += x1 * e3;
            acc[2][0] += x2 * e0; acc[2][1] += x2 * e1; acc[2][2] += x2 * e2; acc[2][3] += x2 * e3;
            acc[3][0] += x3 * e0; acc[3][1] += x3 * e1; acc[3][2] += x3 * e2; acc[3][3] += x3 * e3;
        }
    }
#pragma unroll
    for (int ri = 0; ri < 4; ++ri) {
        int bb = ty * 4 + ri;
#pragma unroll
        for (int cj = 0; cj < 4; ++cj)
            out[(size_t)bb * 32000 + j0 + tx * 4 + cj] = acc[ri][cj];
    }
}

// ---------------------------------------------------------------------------
extern "C" void kernel_launch(void* const* d_in, const int* in_sizes, int n_in,
                              void* d_out, int out_size, void* d_ws, size_t ws_size,
                              hipStream_t stream) {
    const int*      tok   = (const int*)d_in[0];
    const float*    h0    = (const float*)d_in[1];
    const float*    c0    = (const float*)d_in[2];
    const float*    enc   = (const float*)d_in[3];
    const unsigned* mask  = (const unsigned*)d_in[4];
    const float*    table = (const float*)d_in[5];
    const float*    We    = (const float*)d_in[6];
    const float*    Wd    = (const float*)d_in[7];
    const float*    va    = (const float*)d_in[8];
    const float*    Wih   = (const float*)d_in[9];
    const float*    Whh   = (const float*)d_in[10];
    const float*    bih   = (const float*)d_in[11];
    const float*    bhh   = (const float*)d_in[12];
    const float*    Wo    = (const float*)d_in[13];
    const float*    bo    = (const float*)d_in[14];

    float* out    = (float*)d_out;
    float* logits = out;                      // 64*32000 = 2048000
    float* out_h  = out + 2048000;            // 65536
    float* out_c  = out + 2048000 + 65536;    // 65536
    float* out_w  = out + 2048000 + 131072;   // 32768

    float* ws     = (float*)d_ws;
    float* emb    = ws;             // 32768
    float* dp     = ws + 32768;     // 16384
    float* scores = ws + 49152;     // 32768
    float* ctx    = ws + 81920;     // 65536
    float* big    = ws + 147456;    // 524288 floats (ctxp / gates p7 / readout Tp)
    float* T      = ws + 671744;    // 32768
    ushort* Wbf   = (ushort*)(ws + 704512);   // 262144 bf16 (131072 float-slots)
    float* stats  = ws + 835584;    // 1024

    float* ctxp     = big;          // 64*8*1024 partial contexts
    float* gates_p0 = logits;       // kc 0..6 partials, later overwritten by k_logits
    float* gates_p7 = big;          // kc 7 partial (after ctxp consumed)
    float* Tp       = big;          // readout partials (after k_lstm consumed gates)

    k_prep        <<<384, 256, 0, stream>>>(tok, table, We, h0, Wd, emb, Wbf, dp);
    k_scores_ctx  <<<512, 256, 0, stream>>>(enc, Wbf, dp, va, mask, scores, stats, ctxp);
    k_ctx_fin     <<<64, 256, 0, stream>>>(stats, scores, ctxp, out_w, ctx);
    k_gates_part  <<<dim3(64, 8), 256, 0, stream>>>(emb, ctx, h0, Wih, Whh, gates_p0, gates_p7);
    k_lstm        <<<256, 256, 0, stream>>>(gates_p0, gates_p7, bih, bhh, c0, out_h, out_c);
    k_readout_part<<<dim3(32, 16), 256, 0, stream>>>(out_h, ctx, emb, Wo, Tp);
    k_readout_fin <<<128, 256, 0, stream>>>(Tp, bo, T);
    k_logits      <<<500, 256, 0, stream>>>(T, table, logits);
}